// Round 4
// baseline (457.323 us; speedup 1.0000x reference)
//
#include <hip/hip_runtime.h>
#include <math.h>

// HybridSNN: time-collapsed spiking CNN (exact fp32 replication, bit-exact orders).
//  kA: conv0+BN+ReLU+maxpool (+folded weight transposes) -> h [256][16][1025] f32
//  kB: conv1 + 16-step LIF (const inp)  -> m1   [256][32][520]  u16 bitmask over t
//  kD: maxpool(OR) + conv2 over bits + LIF2 -> s2 [256][64][132] u16
//      (m1 staged in LDS; static-offset ds_reads; acc[4][16]/thread)
//  kE: popcount-mean + fc1 + LIF3 + fc2 -> out  [256][5]        f32

#define NB 256
#define LX 4097
#define LQ 2049
#define LP 1025
#define LJ1 513
#define LP1 257
#define LJ2 129

#define M1S 520
#define S2S 132

typedef float f32x4 __attribute__((ext_vector_type(4)));

__global__ __launch_bounds__(256) void kA_conv0(const float* __restrict__ x,
                                                const float* __restrict__ w0,
                                                const float* __restrict__ b0,
                                                const float* __restrict__ bng,
                                                const float* __restrict__ bnb,
                                                const float* __restrict__ bnm,
                                                const float* __restrict__ bnv,
                                                float* __restrict__ h,
                                                const float* __restrict__ w1,
                                                const float* __restrict__ w2,
                                                float* __restrict__ w1t,
                                                float* __restrict__ w2t) {
  __shared__ float xs[828];
  __shared__ float rs_l[16];
  int bid = blockIdx.x;
  int b = bid / 5, pt = bid % 5;
  int P0 = pt * 205;
  int tid = threadIdx.x;
  if (tid < 16) rs_l[tid] = (float)(1.0 / sqrt((double)bnv[tid] + 1e-5));
  const float* xb = x + (size_t)b * LX;
  int x0 = 4 * P0 - 5;
  for (int i = tid; i < 828; i += 256) {
    int gi = x0 + i;
    xs[i] = (gi >= 0 && gi < LX) ? xb[gi] : 0.f;
  }
  __syncthreads();
  if (tid < 205) {
    int p = P0 + tid;
    float win[12];
    {
      const f32x4* xv = (const f32x4*)xs;
      f32x4 a = xv[tid];
      f32x4 bq = xv[tid + 1];
      f32x4 cq = xv[tid + 2];
      win[0] = a.x; win[1] = a.y; win[2] = a.z; win[3] = a.w;
      win[4] = bq.x; win[5] = bq.y; win[6] = bq.z; win[7] = bq.w;
      win[8] = cq.x; win[9] = cq.y; win[10] = cq.z; win[11] = cq.w;
    }
    for (int c = 0; c < 16; ++c) {
      float wv[7];
#pragma unroll
      for (int k = 0; k < 7; ++k) wv[k] = w0[c * 7 + k];
      float rs = rs_l[c], g = bng[c], bb = bnb[c], m = bnm[c], bc = b0[c];
      float hm = -INFINITY;
#pragma unroll
      for (int dq = -1; dq <= 1; ++dq) {
        int q = 2 * p + dq;
        if (q < 0 || q >= LQ) continue;
        float s = 0.f;
        int base = 2 * dq + 2;
#pragma unroll
        for (int k = 0; k < 7; ++k) s = fmaf(win[base + k], wv[k], s);
        float y = s + bc;
        y = (y - m) * rs * g + bb;
        y = fmaxf(y, 0.f);
        hm = fmaxf(hm, y);
      }
      h[((size_t)b * 16 + c) * LP + p] = hm;
    }
  }
  // folded weight transposes (blocks 0..15); kB/kD launch after kA completes
  if (bid < 16) {
    for (int idx = bid * 256 + tid; idx < 32 * 16 * 5; idx += 4096) {
      int k = idx % 5; int r = idx / 5; int ic = r % 16; int c = r / 16;
      w1t[(ic * 5 + k) * 32 + c] = w1[idx];
    }
    for (int idx = bid * 256 + tid; idx < 64 * 32 * 3; idx += 4096) {
      int k = idx % 3; int r = idx / 3; int c = r % 32; int oc = r / 32;
      w2t[(c * 3 + k) * 64 + oc] = w2[idx];
    }
  }
}

__global__ __launch_bounds__(256) void kB_conv1_lif(const float* __restrict__ h,
                                                    const float* __restrict__ w1t_g,
                                                    const float* __restrict__ b1,
                                                    unsigned short* __restrict__ m1) {
  __shared__ float hs[16 * 260];
  __shared__ float wl[16 * 5 * 32];
  int bid = blockIdx.x;
  int b = bid / 5, jt = bid % 5;
  int J0 = jt * 128;
  int tid = threadIdx.x;
  int c = tid & 31, jg = tid >> 5;

  {
    const float* hb = h + (size_t)b * 16 * LP;
    int p0 = 2 * J0 - 2;
    for (int i = tid; i < 16 * 260; i += 256) {
      int ic = i / 260, q = i - ic * 260;
      int p = p0 + q;
      hs[i] = (p >= 0 && p < LP) ? hb[ic * LP + p] : 0.f;
    }
    for (int i = tid; i < 2560; i += 256) wl[i] = w1t_g[i];
  }
  __syncthreads();
  int jbase = J0 + jg * 16;
  if (jbase > 512) return;

  float acc[16];
#pragma unroll
  for (int i = 0; i < 16; ++i) acc[i] = 0.f;

  for (int ic = 0; ic < 16; ++ic) {
    float win[36];
    const f32x4* row = (const f32x4*)(hs + ic * 260 + 32 * jg);
#pragma unroll
    for (int i = 0; i < 9; ++i) {
      f32x4 v = row[i];
      win[4 * i] = v.x; win[4 * i + 1] = v.y; win[4 * i + 2] = v.z; win[4 * i + 3] = v.w;
    }
    float wv[5];
#pragma unroll
    for (int k = 0; k < 5; ++k) wv[k] = wl[(ic * 5 + k) * 32 + c];
#pragma unroll
    for (int j = 0; j < 16; ++j) {
#pragma unroll
      for (int k = 0; k < 5; ++k) acc[j] = fmaf(win[2 * j + k], wv[k], acc[j]);
    }
  }

  float bc = b1[c];
  unsigned mskv[16];
#pragma unroll
  for (int j = 0; j < 16; ++j) {
    float xin = acc[j] + bc;
    float v = 0.f; unsigned mm = 0;
#pragma unroll
    for (int t = 0; t < 16; ++t) {
      v = v + (xin - v) * 0.5f;
      if (v >= 1.f) { mm |= (1u << t); v = 0.f; }
    }
    mskv[j] = mm;
  }
  size_t rowo = ((size_t)b * 32 + c) * M1S + jbase;
  if (jbase + 15 < LJ1) {
    uint4 u0, u1;
    u0.x = mskv[0] | (mskv[1] << 16);
    u0.y = mskv[2] | (mskv[3] << 16);
    u0.z = mskv[4] | (mskv[5] << 16);
    u0.w = mskv[6] | (mskv[7] << 16);
    u1.x = mskv[8] | (mskv[9] << 16);
    u1.y = mskv[10] | (mskv[11] << 16);
    u1.z = mskv[12] | (mskv[13] << 16);
    u1.w = mskv[14] | (mskv[15] << 16);
    *(uint4*)(m1 + rowo) = u0;
    *(uint4*)(m1 + rowo + 8) = u1;
  } else {
    for (int j = 0; j < 16; ++j)
      if (jbase + j < LJ1) m1[rowo + j] = (unsigned short)mskv[j];
  }
}

// kD: maxpool(OR) + conv2 over bitfloats + LIF2.
// Block = (b, jt): 16 j x 64 oc. Thread = 1 j x 4 oc x 16 t.
// m1 slice staged in LDS; F chunked 4 channels; all ds_reads base+imm-offset.
__global__ __launch_bounds__(256, 4) void kD_conv2_lif(const unsigned short* __restrict__ m1,
                                                       const float* __restrict__ w2t_g,
                                                       const float* __restrict__ b2,
                                                       unsigned short* __restrict__ s2) {
  __shared__ __align__(16) float wl[6144];              // 24576 B
  __shared__ __align__(16) float F[4 * 33 * 20];        // 10560 B
  __shared__ __align__(8) unsigned short mbuf[32 * 68]; //  4352 B  -> total 39488 B
  int bid = blockIdx.x;
  int b = bid / 9, jt = bid % 9;
  int J0 = jt * 16;
  int tid = threadIdx.x;
  int ocg = tid & 15;   // oc group of 4
  int jl = tid >> 4;    // 0..15

  for (int i = tid; i < 6144; i += 256) wl[i] = w2t_g[i];

  const unsigned short* m1b = m1 + (size_t)b * 32 * M1S;
  int qbase = 4 * J0 - 4;
  if (jt >= 1 && jt <= 7) {
    // interior: q in [qbase, qbase+67] subset of [0,512] -> unguarded uint2 loads
    for (int i = tid; i < 32 * 17; i += 256) {
      int c = i / 17, u = i - c * 17;
      uint2 v = *(const uint2*)(m1b + (size_t)c * M1S + qbase + 4 * u);
      *(uint2*)(mbuf + c * 68 + 4 * u) = v;
    }
  } else {
    for (int i = tid; i < 32 * 68; i += 256) {
      int c = i / 68, u = i - c * 68;
      int q = qbase + u;
      mbuf[i] = (q >= 0 && q <= 512) ? m1b[(size_t)c * M1S + q] : (unsigned short)0;
    }
  }

  float acc[4][16];
#pragma unroll
  for (int o = 0; o < 4; ++o)
#pragma unroll
    for (int t = 0; t < 16; ++t) acc[o][t] = 0.f;

  __syncthreads();

  const float* wbase = wl + ocg * 4;        // + chd*768 + (cl*3+k)*64 (imm)
  const float* fbase = F + 2 * jl * 20;     // + (cl*33+k)*20 (imm)

  for (int chd = 0; chd < 8; ++chd) {
    // build F for channels chd*4 .. chd*4+3 (maxpool-OR folded; reads LDS mbuf only)
    {
      int it = tid;
      if (it < 132) {
        int cl = it / 33, ridx = it - cl * 33;
        int c = chd * 4 + cl;
        int p = 2 * J0 - 1 + ridx;
        unsigned m = 0;
        if (p >= 0 && p < LP1) {
          const unsigned short* mr = mbuf + c * 68;
          int l0 = 2 * ridx + 1;
          m = (unsigned)mr[l0] | (unsigned)mr[l0 + 1] | (unsigned)mr[l0 + 2];
        }
        f32x4* Fr = (f32x4*)(F + (cl * 33 + ridx) * 20);
        f32x4 f0, f1, f2, f3;
        f0.x = (float)(m & 1u);         f0.y = (float)((m >> 1) & 1u);
        f0.z = (float)((m >> 2) & 1u);  f0.w = (float)((m >> 3) & 1u);
        f1.x = (float)((m >> 4) & 1u);  f1.y = (float)((m >> 5) & 1u);
        f1.z = (float)((m >> 6) & 1u);  f1.w = (float)((m >> 7) & 1u);
        f2.x = (float)((m >> 8) & 1u);  f2.y = (float)((m >> 9) & 1u);
        f2.z = (float)((m >> 10) & 1u); f2.w = (float)((m >> 11) & 1u);
        f3.x = (float)((m >> 12) & 1u); f3.y = (float)((m >> 13) & 1u);
        f3.z = (float)((m >> 14) & 1u); f3.w = (float)((m >> 15) & 1u);
        Fr[0] = f0; Fr[1] = f1; Fr[2] = f2; Fr[3] = f3;
      }
    }
    __syncthreads();

    const float* wch = wbase + chd * 768;   // (chd*4)*3*64
#pragma unroll
    for (int cl = 0; cl < 4; ++cl) {
#pragma unroll
      for (int k = 0; k < 3; ++k) {
        f32x4 wv = *(const f32x4*)(wch + (cl * 3 + k) * 64);
        const f32x4* Fr = (const f32x4*)(fbase + (cl * 33 + k) * 20);
        f32x4 fv[4];
        fv[0] = Fr[0]; fv[1] = Fr[1]; fv[2] = Fr[2]; fv[3] = Fr[3];
#pragma unroll
        for (int o = 0; o < 4; ++o)
#pragma unroll
          for (int t = 0; t < 16; ++t)
            acc[o][t] = fmaf(wv[o], fv[t >> 2][t & 3], acc[o][t]);
      }
    }
    __syncthreads();
  }

  int j = J0 + jl;
  if (j < LJ2) {
#pragma unroll
    for (int o = 0; o < 4; ++o) {
      int oc = ocg * 4 + o;
      float bc = b2[oc];
      float v = 0.f; unsigned mm = 0;
#pragma unroll
      for (int t = 0; t < 16; ++t) {
        float xin = acc[o][t] + bc;
        v = v + (xin - v) * 0.5f;
        if (v >= 1.f) { mm |= (1u << t); v = 0.f; }
      }
      s2[((size_t)b * 64 + oc) * S2S + j] = (unsigned short)mm;
    }
  }
}

__global__ __launch_bounds__(256) void kE_head(const unsigned short* __restrict__ s2,
                                               const float* __restrict__ fc1w,
                                               const float* __restrict__ fc1b,
                                               const float* __restrict__ fc2w,
                                               const float* __restrict__ fc2b,
                                               float* __restrict__ out) {
  __shared__ float meanL[16][64];
  __shared__ unsigned s3m[32];
  int b = blockIdx.x;
  int tid = threadIdx.x;
  int oc = tid >> 2, part = tid & 3;

  const unsigned short* row = s2 + ((size_t)b * 64 + oc) * S2S + part * 32;
  int cnt[16];
#pragma unroll
  for (int t = 0; t < 16; ++t) cnt[t] = 0;
  const uint2* rv = (const uint2*)row;   // byte offset (b*64+oc)*264 + part*64: 8-aligned
#pragma unroll
  for (int u = 0; u < 8; ++u) {
    uint2 v = rv[u];
    unsigned w[4] = {v.x & 0xffffu, v.x >> 16, v.y & 0xffffu, v.y >> 16};
#pragma unroll
    for (int e = 0; e < 4; ++e)
#pragma unroll
      for (int t = 0; t < 16; ++t) cnt[t] += (int)((w[e] >> t) & 1u);
  }
  if (part == 3) {
    unsigned m = row[32];  // j = 128
#pragma unroll
    for (int t = 0; t < 16; ++t) cnt[t] += (int)((m >> t) & 1u);
  }
  // reduce across the 4 parts (adjacent lanes)
#pragma unroll
  for (int t = 0; t < 16; ++t) {
    cnt[t] += __shfl_xor(cnt[t], 1);
    cnt[t] += __shfl_xor(cnt[t], 2);
  }
  if (part == 0) {
#pragma unroll
    for (int t = 0; t < 16; ++t) meanL[t][oc] = (float)cnt[t] / 129.f;
  }
  __syncthreads();

  if (tid < 32) {
    int o = tid;
    const float* wrow = fc1w + o * 64;
    float bb = fc1b[o];
    float v = 0.f;
    unsigned msk = 0;
    for (int t = 0; t < 16; ++t) {
      float s = 0.f;
      for (int d = 0; d < 64; ++d) s = fmaf(meanL[t][d], wrow[d], s);
      float xin = s + bb;
      v = v + (xin - v) * 0.5f;
      if (v >= 1.f) { msk |= (1u << t); v = 0.f; }
    }
    s3m[o] = msk;
  }
  __syncthreads();

  if (tid < 5) {
    int q = tid;
    const float* wrow = fc2w + q * 32;
    float bb = fc2b[q];
    float accs = 0.f;
    for (int t = 0; t < 16; ++t) {
      float s = 0.f;
      for (int o = 0; o < 32; ++o) s += (((s3m[o] >> t) & 1u) ? wrow[o] : 0.f);
      accs += (s + bb);
    }
    out[b * 5 + q] = accs / 16.f;
  }
}

extern "C" void kernel_launch(void* const* d_in, const int* in_sizes, int n_in,
                              void* d_out, int out_size, void* d_ws, size_t ws_size,
                              hipStream_t stream) {
  const float* x   = (const float*)d_in[0];
  const float* w0  = (const float*)d_in[1];
  const float* b0  = (const float*)d_in[2];
  const float* bng = (const float*)d_in[3];
  const float* bnb = (const float*)d_in[4];
  const float* bnm = (const float*)d_in[5];
  const float* bnv = (const float*)d_in[6];
  const float* w1  = (const float*)d_in[7];
  const float* b1  = (const float*)d_in[8];
  const float* w2  = (const float*)d_in[9];
  const float* b2  = (const float*)d_in[10];
  const float* f1w = (const float*)d_in[11];
  const float* f1b = (const float*)d_in[12];
  const float* f2w = (const float*)d_in[13];
  const float* f2b = (const float*)d_in[14];
  float* out = (float*)d_out;

  char* ws = (char*)d_ws;
  size_t sz_h  = (size_t)NB * 16 * LP * 4;       // 16,793,600
  size_t sz_m1 = (size_t)NB * 32 * M1S * 2;      //  8,519,680
  size_t sz_s2 = (size_t)NB * 64 * S2S * 2;      //  4,325,376
  size_t off_m1 = sz_h;
  size_t off_s2 = off_m1 + sz_m1;
  size_t off_sm = off_s2 + sz_s2;
  size_t sz_sm = (2560 + 6144) * 4;
  if (ws_size < off_sm + sz_sm) return;          // ~29.7 MB needed

  float* h = (float*)ws;
  unsigned short* m1 = (unsigned short*)(ws + off_m1);
  unsigned short* s2 = (unsigned short*)(ws + off_s2);
  float* w1t = (float*)(ws + off_sm);
  float* w2t = w1t + 2560;

  kA_conv0<<<NB * 5, 256, 0, stream>>>(x, w0, b0, bng, bnb, bnm, bnv, h, w1, w2, w1t, w2t);
  kB_conv1_lif<<<NB * 5, 256, 0, stream>>>(h, w1t, b1, m1);
  kD_conv2_lif<<<NB * 9, 256, 0, stream>>>(m1, w2t, b2, s2);
  kE_head<<<NB, 64, 0, stream>>>(s2, f1w, f1b, f2w, f2b, out);
}

// Round 5
// 187.616 us; speedup vs baseline: 2.4375x; 2.4375x over previous
//
#include <hip/hip_runtime.h>
#include <math.h>

// HybridSNN: time-collapsed spiking CNN (exact fp32 replication, bit-exact orders).
//  kA: conv0+BN+ReLU+maxpool (+folded weight transposes) -> h [256][16][1025] f32
//  kB: conv1 + 16-step LIF (const inp)  -> m1   [256][32][520]  u16 bitmask over t
//  kD: maxpool(OR) + conv2 over bits + LIF2 -> s2 [256][64][132] u16
//      (m1 staged in LDS; static-offset ds_reads; acc[4][16]/thread; NO reg cap —
//       launch_bounds(256,4) in R4 forced VGPR=64 -> 2GB scratch spill, 441us)
//  kE: popcount-mean + fc1 + LIF3 + fc2 -> out  [256][5]        f32  (256 thr)

#define NB 256
#define LX 4097
#define LQ 2049
#define LP 1025
#define LJ1 513
#define LP1 257
#define LJ2 129

#define M1S 520
#define S2S 132

typedef float f32x4 __attribute__((ext_vector_type(4)));

__global__ __launch_bounds__(256) void kA_conv0(const float* __restrict__ x,
                                                const float* __restrict__ w0,
                                                const float* __restrict__ b0,
                                                const float* __restrict__ bng,
                                                const float* __restrict__ bnb,
                                                const float* __restrict__ bnm,
                                                const float* __restrict__ bnv,
                                                float* __restrict__ h,
                                                const float* __restrict__ w1,
                                                const float* __restrict__ w2,
                                                float* __restrict__ w1t,
                                                float* __restrict__ w2t) {
  __shared__ float xs[828];
  __shared__ float rs_l[16];
  int bid = blockIdx.x;
  int b = bid / 5, pt = bid % 5;
  int P0 = pt * 205;
  int tid = threadIdx.x;
  if (tid < 16) rs_l[tid] = (float)(1.0 / sqrt((double)bnv[tid] + 1e-5));
  const float* xb = x + (size_t)b * LX;
  int x0 = 4 * P0 - 5;
  for (int i = tid; i < 828; i += 256) {
    int gi = x0 + i;
    xs[i] = (gi >= 0 && gi < LX) ? xb[gi] : 0.f;
  }
  __syncthreads();
  if (tid < 205) {
    int p = P0 + tid;
    float win[12];
    {
      const f32x4* xv = (const f32x4*)xs;
      f32x4 a = xv[tid];
      f32x4 bq = xv[tid + 1];
      f32x4 cq = xv[tid + 2];
      win[0] = a.x; win[1] = a.y; win[2] = a.z; win[3] = a.w;
      win[4] = bq.x; win[5] = bq.y; win[6] = bq.z; win[7] = bq.w;
      win[8] = cq.x; win[9] = cq.y; win[10] = cq.z; win[11] = cq.w;
    }
    for (int c = 0; c < 16; ++c) {
      float wv[7];
#pragma unroll
      for (int k = 0; k < 7; ++k) wv[k] = w0[c * 7 + k];
      float rs = rs_l[c], g = bng[c], bb = bnb[c], m = bnm[c], bc = b0[c];
      float hm = -INFINITY;
#pragma unroll
      for (int dq = -1; dq <= 1; ++dq) {
        int q = 2 * p + dq;
        if (q < 0 || q >= LQ) continue;
        float s = 0.f;
        int base = 2 * dq + 2;
#pragma unroll
        for (int k = 0; k < 7; ++k) s = fmaf(win[base + k], wv[k], s);
        float y = s + bc;
        y = (y - m) * rs * g + bb;
        y = fmaxf(y, 0.f);
        hm = fmaxf(hm, y);
      }
      h[((size_t)b * 16 + c) * LP + p] = hm;
    }
  }
  // folded weight transposes (blocks 0..15); kB/kD launch after kA completes
  if (bid < 16) {
    for (int idx = bid * 256 + tid; idx < 32 * 16 * 5; idx += 4096) {
      int k = idx % 5; int r = idx / 5; int ic = r % 16; int c = r / 16;
      w1t[(ic * 5 + k) * 32 + c] = w1[idx];
    }
    for (int idx = bid * 256 + tid; idx < 64 * 32 * 3; idx += 4096) {
      int k = idx % 3; int r = idx / 3; int c = r % 32; int oc = r / 32;
      w2t[(c * 3 + k) * 64 + oc] = w2[idx];
    }
  }
}

__global__ __launch_bounds__(256) void kB_conv1_lif(const float* __restrict__ h,
                                                    const float* __restrict__ w1t_g,
                                                    const float* __restrict__ b1,
                                                    unsigned short* __restrict__ m1) {
  __shared__ float hs[16 * 260];
  __shared__ float wl[16 * 5 * 32];
  int bid = blockIdx.x;
  int b = bid / 5, jt = bid % 5;
  int J0 = jt * 128;
  int tid = threadIdx.x;
  int c = tid & 31, jg = tid >> 5;

  {
    const float* hb = h + (size_t)b * 16 * LP;
    int p0 = 2 * J0 - 2;
    for (int i = tid; i < 16 * 260; i += 256) {
      int ic = i / 260, q = i - ic * 260;
      int p = p0 + q;
      hs[i] = (p >= 0 && p < LP) ? hb[ic * LP + p] : 0.f;
    }
    for (int i = tid; i < 2560; i += 256) wl[i] = w1t_g[i];
  }
  __syncthreads();
  int jbase = J0 + jg * 16;
  if (jbase > 512) return;

  float acc[16];
#pragma unroll
  for (int i = 0; i < 16; ++i) acc[i] = 0.f;

  for (int ic = 0; ic < 16; ++ic) {
    float win[36];
    const f32x4* row = (const f32x4*)(hs + ic * 260 + 32 * jg);
#pragma unroll
    for (int i = 0; i < 9; ++i) {
      f32x4 v = row[i];
      win[4 * i] = v.x; win[4 * i + 1] = v.y; win[4 * i + 2] = v.z; win[4 * i + 3] = v.w;
    }
    float wv[5];
#pragma unroll
    for (int k = 0; k < 5; ++k) wv[k] = wl[(ic * 5 + k) * 32 + c];
#pragma unroll
    for (int j = 0; j < 16; ++j) {
#pragma unroll
      for (int k = 0; k < 5; ++k) acc[j] = fmaf(win[2 * j + k], wv[k], acc[j]);
    }
  }

  float bc = b1[c];
  unsigned mskv[16];
#pragma unroll
  for (int j = 0; j < 16; ++j) {
    float xin = acc[j] + bc;
    float v = 0.f; unsigned mm = 0;
#pragma unroll
    for (int t = 0; t < 16; ++t) {
      v = v + (xin - v) * 0.5f;
      if (v >= 1.f) { mm |= (1u << t); v = 0.f; }
    }
    mskv[j] = mm;
  }
  size_t rowo = ((size_t)b * 32 + c) * M1S + jbase;
  if (jbase + 15 < LJ1) {
    uint4 u0, u1;
    u0.x = mskv[0] | (mskv[1] << 16);
    u0.y = mskv[2] | (mskv[3] << 16);
    u0.z = mskv[4] | (mskv[5] << 16);
    u0.w = mskv[6] | (mskv[7] << 16);
    u1.x = mskv[8] | (mskv[9] << 16);
    u1.y = mskv[10] | (mskv[11] << 16);
    u1.z = mskv[12] | (mskv[13] << 16);
    u1.w = mskv[14] | (mskv[15] << 16);
    *(uint4*)(m1 + rowo) = u0;
    *(uint4*)(m1 + rowo + 8) = u1;
  } else {
    for (int j = 0; j < 16; ++j)
      if (jbase + j < LJ1) m1[rowo + j] = (unsigned short)mskv[j];
  }
}

// kD: maxpool(OR) + conv2 over bitfloats + LIF2.
// Block = (b, jt): 16 j x 64 oc. Thread = 1 j x 4 oc x 16 t.
// m1 slice staged in LDS; F chunked 4 channels; all ds_reads base+imm-offset.
__global__ __launch_bounds__(256) void kD_conv2_lif(const unsigned short* __restrict__ m1,
                                                    const float* __restrict__ w2t_g,
                                                    const float* __restrict__ b2,
                                                    unsigned short* __restrict__ s2) {
  __shared__ __align__(16) float wl[6144];              // 24576 B
  __shared__ __align__(16) float F[4 * 33 * 20];        // 10560 B
  __shared__ __align__(8) unsigned short mbuf[32 * 68]; //  4352 B  -> total 39488 B
  int bid = blockIdx.x;
  int b = bid / 9, jt = bid % 9;
  int J0 = jt * 16;
  int tid = threadIdx.x;
  int ocg = tid & 15;   // oc group of 4
  int jl = tid >> 4;    // 0..15

  for (int i = tid; i < 6144; i += 256) wl[i] = w2t_g[i];

  const unsigned short* m1b = m1 + (size_t)b * 32 * M1S;
  int qbase = 4 * J0 - 4;
  if (jt >= 1 && jt <= 7) {
    // interior: q in [qbase, qbase+67] subset of [0,512] -> unguarded uint2 loads
    for (int i = tid; i < 32 * 17; i += 256) {
      int c = i / 17, u = i - c * 17;
      uint2 v = *(const uint2*)(m1b + (size_t)c * M1S + qbase + 4 * u);
      *(uint2*)(mbuf + c * 68 + 4 * u) = v;
    }
  } else {
    for (int i = tid; i < 32 * 68; i += 256) {
      int c = i / 68, u = i - c * 68;
      int q = qbase + u;
      mbuf[i] = (q >= 0 && q <= 512) ? m1b[(size_t)c * M1S + q] : (unsigned short)0;
    }
  }

  float acc[4][16];
#pragma unroll
  for (int o = 0; o < 4; ++o)
#pragma unroll
    for (int t = 0; t < 16; ++t) acc[o][t] = 0.f;

  __syncthreads();

  const float* wbase = wl + ocg * 4;        // + chd*768 + (cl*3+k)*64 (imm)
  const float* fbase = F + 2 * jl * 20;     // + (cl*33+k)*20 (imm)

  for (int chd = 0; chd < 8; ++chd) {
    // build F for channels chd*4 .. chd*4+3 (maxpool-OR folded; reads LDS mbuf only)
    {
      int it = tid;
      if (it < 132) {
        int cl = it / 33, ridx = it - cl * 33;
        int c = chd * 4 + cl;
        int p = 2 * J0 - 1 + ridx;
        unsigned m = 0;
        if (p >= 0 && p < LP1) {
          const unsigned short* mr = mbuf + c * 68;
          int l0 = 2 * ridx + 1;
          m = (unsigned)mr[l0] | (unsigned)mr[l0 + 1] | (unsigned)mr[l0 + 2];
        }
        f32x4* Fr = (f32x4*)(F + (cl * 33 + ridx) * 20);
        f32x4 f0, f1, f2, f3;
        f0.x = (float)(m & 1u);         f0.y = (float)((m >> 1) & 1u);
        f0.z = (float)((m >> 2) & 1u);  f0.w = (float)((m >> 3) & 1u);
        f1.x = (float)((m >> 4) & 1u);  f1.y = (float)((m >> 5) & 1u);
        f1.z = (float)((m >> 6) & 1u);  f1.w = (float)((m >> 7) & 1u);
        f2.x = (float)((m >> 8) & 1u);  f2.y = (float)((m >> 9) & 1u);
        f2.z = (float)((m >> 10) & 1u); f2.w = (float)((m >> 11) & 1u);
        f3.x = (float)((m >> 12) & 1u); f3.y = (float)((m >> 13) & 1u);
        f3.z = (float)((m >> 14) & 1u); f3.w = (float)((m >> 15) & 1u);
        Fr[0] = f0; Fr[1] = f1; Fr[2] = f2; Fr[3] = f3;
      }
    }
    __syncthreads();

    const float* wch = wbase + chd * 768;   // (chd*4)*3*64
#pragma unroll
    for (int cl = 0; cl < 4; ++cl) {
#pragma unroll
      for (int k = 0; k < 3; ++k) {
        f32x4 wv = *(const f32x4*)(wch + (cl * 3 + k) * 64);
        const f32x4* Fr = (const f32x4*)(fbase + (cl * 33 + k) * 20);
        f32x4 fv[4];
        fv[0] = Fr[0]; fv[1] = Fr[1]; fv[2] = Fr[2]; fv[3] = Fr[3];
#pragma unroll
        for (int o = 0; o < 4; ++o)
#pragma unroll
          for (int t = 0; t < 16; ++t)
            acc[o][t] = fmaf(wv[o], fv[t >> 2][t & 3], acc[o][t]);
      }
    }
    __syncthreads();
  }

  int j = J0 + jl;
  if (j < LJ2) {
#pragma unroll
    for (int o = 0; o < 4; ++o) {
      int oc = ocg * 4 + o;
      float bc = b2[oc];
      float v = 0.f; unsigned mm = 0;
#pragma unroll
      for (int t = 0; t < 16; ++t) {
        float xin = acc[o][t] + bc;
        v = v + (xin - v) * 0.5f;
        if (v >= 1.f) { mm |= (1u << t); v = 0.f; }
      }
      s2[((size_t)b * 64 + oc) * S2S + j] = (unsigned short)mm;
    }
  }
}

__global__ __launch_bounds__(256) void kE_head(const unsigned short* __restrict__ s2,
                                               const float* __restrict__ fc1w,
                                               const float* __restrict__ fc1b,
                                               const float* __restrict__ fc2w,
                                               const float* __restrict__ fc2b,
                                               float* __restrict__ out) {
  __shared__ float meanL[16][64];
  __shared__ unsigned s3m[32];
  int b = blockIdx.x;
  int tid = threadIdx.x;
  int oc = tid >> 2, part = tid & 3;

  const unsigned short* row = s2 + ((size_t)b * 64 + oc) * S2S + part * 32;
  int cnt[16];
#pragma unroll
  for (int t = 0; t < 16; ++t) cnt[t] = 0;
  const uint2* rv = (const uint2*)row;   // byte offset (b*64+oc)*264 + part*64: 8-aligned
#pragma unroll
  for (int u = 0; u < 8; ++u) {
    uint2 v = rv[u];
    unsigned w[4] = {v.x & 0xffffu, v.x >> 16, v.y & 0xffffu, v.y >> 16};
#pragma unroll
    for (int e = 0; e < 4; ++e)
#pragma unroll
      for (int t = 0; t < 16; ++t) cnt[t] += (int)((w[e] >> t) & 1u);
  }
  if (part == 3) {
    unsigned m = row[32];  // j = 128
#pragma unroll
    for (int t = 0; t < 16; ++t) cnt[t] += (int)((m >> t) & 1u);
  }
  // reduce across the 4 parts (adjacent lanes)
#pragma unroll
  for (int t = 0; t < 16; ++t) {
    cnt[t] += __shfl_xor(cnt[t], 1);
    cnt[t] += __shfl_xor(cnt[t], 2);
  }
  if (part == 0) {
#pragma unroll
    for (int t = 0; t < 16; ++t) meanL[t][oc] = (float)cnt[t] / 129.f;
  }
  __syncthreads();

  if (tid < 32) {
    int o = tid;
    const float* wrow = fc1w + o * 64;
    float bb = fc1b[o];
    float v = 0.f;
    unsigned msk = 0;
    for (int t = 0; t < 16; ++t) {
      float s = 0.f;
      for (int d = 0; d < 64; ++d) s = fmaf(meanL[t][d], wrow[d], s);
      float xin = s + bb;
      v = v + (xin - v) * 0.5f;
      if (v >= 1.f) { msk |= (1u << t); v = 0.f; }
    }
    s3m[o] = msk;
  }
  __syncthreads();

  if (tid < 5) {
    int q = tid;
    const float* wrow = fc2w + q * 32;
    float bb = fc2b[q];
    float accs = 0.f;
    for (int t = 0; t < 16; ++t) {
      float s = 0.f;
      for (int o = 0; o < 32; ++o) s += (((s3m[o] >> t) & 1u) ? wrow[o] : 0.f);
      accs += (s + bb);
    }
    out[b * 5 + q] = accs / 16.f;
  }
}

extern "C" void kernel_launch(void* const* d_in, const int* in_sizes, int n_in,
                              void* d_out, int out_size, void* d_ws, size_t ws_size,
                              hipStream_t stream) {
  const float* x   = (const float*)d_in[0];
  const float* w0  = (const float*)d_in[1];
  const float* b0  = (const float*)d_in[2];
  const float* bng = (const float*)d_in[3];
  const float* bnb = (const float*)d_in[4];
  const float* bnm = (const float*)d_in[5];
  const float* bnv = (const float*)d_in[6];
  const float* w1  = (const float*)d_in[7];
  const float* b1  = (const float*)d_in[8];
  const float* w2  = (const float*)d_in[9];
  const float* b2  = (const float*)d_in[10];
  const float* f1w = (const float*)d_in[11];
  const float* f1b = (const float*)d_in[12];
  const float* f2w = (const float*)d_in[13];
  const float* f2b = (const float*)d_in[14];
  float* out = (float*)d_out;

  char* ws = (char*)d_ws;
  size_t sz_h  = (size_t)NB * 16 * LP * 4;       // 16,793,600
  size_t sz_m1 = (size_t)NB * 32 * M1S * 2;      //  8,519,680
  size_t sz_s2 = (size_t)NB * 64 * S2S * 2;      //  4,325,376
  size_t off_m1 = sz_h;
  size_t off_s2 = off_m1 + sz_m1;
  size_t off_sm = off_s2 + sz_s2;
  size_t sz_sm = (2560 + 6144) * 4;
  if (ws_size < off_sm + sz_sm) return;          // ~29.7 MB needed

  float* h = (float*)ws;
  unsigned short* m1 = (unsigned short*)(ws + off_m1);
  unsigned short* s2 = (unsigned short*)(ws + off_s2);
  float* w1t = (float*)(ws + off_sm);
  float* w2t = w1t + 2560;

  kA_conv0<<<NB * 5, 256, 0, stream>>>(x, w0, b0, bng, bnb, bnm, bnv, h, w1, w2, w1t, w2t);
  kB_conv1_lif<<<NB * 5, 256, 0, stream>>>(h, w1t, b1, m1);
  kD_conv2_lif<<<NB * 9, 256, 0, stream>>>(m1, w2t, b2, s2);
  kE_head<<<NB, 256, 0, stream>>>(s2, f1w, f1b, f2w, f2b, out);
}

// Round 6
// 131.576 us; speedup vs baseline: 3.4757x; 1.4259x over previous
//
#include <hip/hip_runtime.h>
#include <math.h>

// HybridSNN: time-collapsed spiking CNN (exact fp32 replication, bit-exact orders).
//  kA: conv0+BN+ReLU+maxpool (+folded weight transposes) -> h [256][16][1025] f32
//  kB: conv1 + 16-step LIF (const inp)  -> m1   [256][32][520]  u16 bitmask over t
//  kD: maxpool(OR) + conv2 over bits + LIF2 -> s2 [256][132][64] u16 (layout [b][j][oc])
//      wave = 1 j, lanes = 64 oc, 16 t in regs; wave-uniform zero-mask skip (~60%);
//      F broadcasts from LDS; w coalesced from L1. Skipping fmaf(w,0,acc) is bit-exact.
//  kE: popcount-mean + fc1 + LIF3 + fc2 -> out  [256][5]        f32

#define NB 256
#define LX 4097
#define LQ 2049
#define LP 1025
#define LJ1 513
#define LP1 257
#define LJ2 129

#define M1S 520
#define S2R 132   // s2 rows per batch (j padded 129->132)

typedef float f32x4 __attribute__((ext_vector_type(4)));

__global__ __launch_bounds__(256) void kA_conv0(const float* __restrict__ x,
                                                const float* __restrict__ w0,
                                                const float* __restrict__ b0,
                                                const float* __restrict__ bng,
                                                const float* __restrict__ bnb,
                                                const float* __restrict__ bnm,
                                                const float* __restrict__ bnv,
                                                float* __restrict__ h,
                                                const float* __restrict__ w1,
                                                const float* __restrict__ w2,
                                                float* __restrict__ w1t,
                                                float* __restrict__ w2t) {
  __shared__ float xs[828];
  __shared__ float rs_l[16];
  int bid = blockIdx.x;
  int b = bid / 5, pt = bid % 5;
  int P0 = pt * 205;
  int tid = threadIdx.x;
  if (tid < 16) rs_l[tid] = (float)(1.0 / sqrt((double)bnv[tid] + 1e-5));
  const float* xb = x + (size_t)b * LX;
  int x0 = 4 * P0 - 5;
  for (int i = tid; i < 828; i += 256) {
    int gi = x0 + i;
    xs[i] = (gi >= 0 && gi < LX) ? xb[gi] : 0.f;
  }
  __syncthreads();
  if (tid < 205) {
    int p = P0 + tid;
    float win[12];
    {
      const f32x4* xv = (const f32x4*)xs;
      f32x4 a = xv[tid];
      f32x4 bq = xv[tid + 1];
      f32x4 cq = xv[tid + 2];
      win[0] = a.x; win[1] = a.y; win[2] = a.z; win[3] = a.w;
      win[4] = bq.x; win[5] = bq.y; win[6] = bq.z; win[7] = bq.w;
      win[8] = cq.x; win[9] = cq.y; win[10] = cq.z; win[11] = cq.w;
    }
    for (int c = 0; c < 16; ++c) {
      float wv[7];
#pragma unroll
      for (int k = 0; k < 7; ++k) wv[k] = w0[c * 7 + k];
      float rs = rs_l[c], g = bng[c], bb = bnb[c], m = bnm[c], bc = b0[c];
      float hm = -INFINITY;
#pragma unroll
      for (int dq = -1; dq <= 1; ++dq) {
        int q = 2 * p + dq;
        if (q < 0 || q >= LQ) continue;
        float s = 0.f;
        int base = 2 * dq + 2;
#pragma unroll
        for (int k = 0; k < 7; ++k) s = fmaf(win[base + k], wv[k], s);
        float y = s + bc;
        y = (y - m) * rs * g + bb;
        y = fmaxf(y, 0.f);
        hm = fmaxf(hm, y);
      }
      h[((size_t)b * 16 + c) * LP + p] = hm;
    }
  }
  // folded weight transposes (blocks 0..15); kB/kD launch after kA completes
  if (bid < 16) {
    for (int idx = bid * 256 + tid; idx < 32 * 16 * 5; idx += 4096) {
      int k = idx % 5; int r = idx / 5; int ic = r % 16; int c = r / 16;
      w1t[(ic * 5 + k) * 32 + c] = w1[idx];
    }
    for (int idx = bid * 256 + tid; idx < 64 * 32 * 3; idx += 4096) {
      int k = idx % 3; int r = idx / 3; int c = r % 32; int oc = r / 32;
      w2t[(c * 3 + k) * 64 + oc] = w2[idx];
    }
  }
}

__global__ __launch_bounds__(256) void kB_conv1_lif(const float* __restrict__ h,
                                                    const float* __restrict__ w1t_g,
                                                    const float* __restrict__ b1,
                                                    unsigned short* __restrict__ m1) {
  __shared__ float hs[16 * 260];
  __shared__ float wl[16 * 5 * 32];
  int bid = blockIdx.x;
  int b = bid / 5, jt = bid % 5;
  int J0 = jt * 128;
  int tid = threadIdx.x;
  int c = tid & 31, jg = tid >> 5;

  {
    const float* hb = h + (size_t)b * 16 * LP;
    int p0 = 2 * J0 - 2;
    for (int i = tid; i < 16 * 260; i += 256) {
      int ic = i / 260, q = i - ic * 260;
      int p = p0 + q;
      hs[i] = (p >= 0 && p < LP) ? hb[ic * LP + p] : 0.f;
    }
    for (int i = tid; i < 2560; i += 256) wl[i] = w1t_g[i];
  }
  __syncthreads();
  int jbase = J0 + jg * 16;
  if (jbase > 512) return;

  float acc[16];
#pragma unroll
  for (int i = 0; i < 16; ++i) acc[i] = 0.f;

  for (int ic = 0; ic < 16; ++ic) {
    float win[36];
    const f32x4* row = (const f32x4*)(hs + ic * 260 + 32 * jg);
#pragma unroll
    for (int i = 0; i < 9; ++i) {
      f32x4 v = row[i];
      win[4 * i] = v.x; win[4 * i + 1] = v.y; win[4 * i + 2] = v.z; win[4 * i + 3] = v.w;
    }
    float wv[5];
#pragma unroll
    for (int k = 0; k < 5; ++k) wv[k] = wl[(ic * 5 + k) * 32 + c];
#pragma unroll
    for (int j = 0; j < 16; ++j) {
#pragma unroll
      for (int k = 0; k < 5; ++k) acc[j] = fmaf(win[2 * j + k], wv[k], acc[j]);
    }
  }

  float bc = b1[c];
  unsigned mskv[16];
#pragma unroll
  for (int j = 0; j < 16; ++j) {
    float xin = acc[j] + bc;
    float v = 0.f; unsigned mm = 0;
#pragma unroll
    for (int t = 0; t < 16; ++t) {
      v = v + (xin - v) * 0.5f;
      if (v >= 1.f) { mm |= (1u << t); v = 0.f; }
    }
    mskv[j] = mm;
  }
  size_t rowo = ((size_t)b * 32 + c) * M1S + jbase;
  if (jbase + 15 < LJ1) {
    uint4 u0, u1;
    u0.x = mskv[0] | (mskv[1] << 16);
    u0.y = mskv[2] | (mskv[3] << 16);
    u0.z = mskv[4] | (mskv[5] << 16);
    u0.w = mskv[6] | (mskv[7] << 16);
    u1.x = mskv[8] | (mskv[9] << 16);
    u1.y = mskv[10] | (mskv[11] << 16);
    u1.z = mskv[12] | (mskv[13] << 16);
    u1.w = mskv[14] | (mskv[15] << 16);
    *(uint4*)(m1 + rowo) = u0;
    *(uint4*)(m1 + rowo + 8) = u1;
  } else {
    for (int j = 0; j < 16; ++j)
      if (jbase + j < LJ1) m1[rowo + j] = (unsigned short)mskv[j];
  }
}

// kD: maxpool(OR) + conv2 over bitfloats + LIF2, wave-uniform sparsity skip.
// Grid: 256 b x 33 jt. Block: 4 waves; wave w -> j = jt*4 + w; lane = oc.
// Thread: 1 j x 1 oc x 16 t (acc[16]).
__global__ __launch_bounds__(256) void kD_conv2_lif(const unsigned short* __restrict__ m1,
                                                    const float* __restrict__ w2t_g,
                                                    const float* __restrict__ b2,
                                                    unsigned short* __restrict__ s2) {
  __shared__ __align__(16) float F[32 * 9 * 16];  // 18432 B bitfloats
  __shared__ unsigned mval[32 * 9];               //  1152 B masks (skip keys)
  __shared__ unsigned short mbuf[32 * 20];        //  1280 B m1 window
  int bid = blockIdx.x;
  int b = bid / 33, jt = bid % 33;
  int j0 = jt * 4;
  int tid = threadIdx.x;
  int w = tid >> 6;      // wave id = j offset
  int lane = tid & 63;   // oc

  // stage m1 window: q = 4*j0 - 3 + u, u in [0,20)
  const unsigned short* m1b = m1 + (size_t)b * 32 * M1S;
  int qbase = 4 * j0 - 3;
  for (int i = tid; i < 1024; i += 256) {
    int c = i >> 5, u = i & 31;
    if (u < 20) {
      int q = qbase + u;
      mbuf[c * 20 + u] = (q >= 0 && q <= 512) ? m1b[(size_t)c * M1S + q] : (unsigned short)0;
    }
  }
  __syncthreads();

  // build F rows + mval: 288 items = 32 c x 9 positions (maxpool-OR folded)
  for (int it = tid; it < 288; it += 256) {
    int c = it / 9, idx = it - c * 9;
    int p = 2 * j0 - 1 + idx;
    unsigned m = 0;
    if (p >= 0 && p < LP1) {
      const unsigned short* mr = mbuf + c * 20;
      int l0 = 2 * idx;  // q0 = 2p-1 = qbase + 2*idx
      m = (unsigned)mr[l0] | (unsigned)mr[l0 + 1] | (unsigned)mr[l0 + 2];
    }
    mval[it] = m;
    f32x4* Fr = (f32x4*)(F + it * 16);
    f32x4 f0, f1, f2, f3;
    f0.x = (float)(m & 1u);         f0.y = (float)((m >> 1) & 1u);
    f0.z = (float)((m >> 2) & 1u);  f0.w = (float)((m >> 3) & 1u);
    f1.x = (float)((m >> 4) & 1u);  f1.y = (float)((m >> 5) & 1u);
    f1.z = (float)((m >> 6) & 1u);  f1.w = (float)((m >> 7) & 1u);
    f2.x = (float)((m >> 8) & 1u);  f2.y = (float)((m >> 9) & 1u);
    f2.z = (float)((m >> 10) & 1u); f2.w = (float)((m >> 11) & 1u);
    f3.x = (float)((m >> 12) & 1u); f3.y = (float)((m >> 13) & 1u);
    f3.z = (float)((m >> 14) & 1u); f3.w = (float)((m >> 15) & 1u);
    Fr[0] = f0; Fr[1] = f1; Fr[2] = f2; Fr[3] = f3;
  }
  __syncthreads();

  float acc[16];
#pragma unroll
  for (int t = 0; t < 16; ++t) acc[t] = 0.f;

  const float* wrow = w2t_g + lane;  // w2t[(c*3+k)*64 + oc], coalesced, L1-resident
  for (int c = 0; c < 32; ++c) {
    int base9 = c * 9 + 2 * w;
    unsigned mv0 = mval[base9];
    unsigned mv1 = mval[base9 + 1];
    unsigned mv2 = mval[base9 + 2];
    if ((mv0 | mv1 | mv2) == 0u) continue;  // wave-uniform skip (~51% of c)
    const float* wr = wrow + c * 192;
    const f32x4* Fb = (const f32x4*)(F + base9 * 16);
    if (mv0) {
      float wv = wr[0];
      f32x4 fv[4];
      fv[0] = Fb[0]; fv[1] = Fb[1]; fv[2] = Fb[2]; fv[3] = Fb[3];
#pragma unroll
      for (int t = 0; t < 16; ++t) acc[t] = fmaf(wv, fv[t >> 2][t & 3], acc[t]);
    }
    if (mv1) {
      float wv = wr[64];
      f32x4 fv[4];
      fv[0] = Fb[4]; fv[1] = Fb[5]; fv[2] = Fb[6]; fv[3] = Fb[7];
#pragma unroll
      for (int t = 0; t < 16; ++t) acc[t] = fmaf(wv, fv[t >> 2][t & 3], acc[t]);
    }
    if (mv2) {
      float wv = wr[128];
      f32x4 fv[4];
      fv[0] = Fb[8]; fv[1] = Fb[9]; fv[2] = Fb[10]; fv[3] = Fb[11];
#pragma unroll
      for (int t = 0; t < 16; ++t) acc[t] = fmaf(wv, fv[t >> 2][t & 3], acc[t]);
    }
  }

  int j = j0 + w;
  if (j < LJ2) {
    float bc = b2[lane];
    float v = 0.f; unsigned mm = 0;
#pragma unroll
    for (int t = 0; t < 16; ++t) {
      float xin = acc[t] + bc;
      v = v + (xin - v) * 0.5f;
      if (v >= 1.f) { mm |= (1u << t); v = 0.f; }
    }
    s2[((size_t)b * S2R + j) * 64 + lane] = (unsigned short)mm;  // coalesced per wave
  }
}

__global__ __launch_bounds__(256) void kE_head(const unsigned short* __restrict__ s2,
                                               const float* __restrict__ fc1w,
                                               const float* __restrict__ fc1b,
                                               const float* __restrict__ fc2w,
                                               const float* __restrict__ fc2b,
                                               float* __restrict__ out) {
  __shared__ float meanL[16][64];
  __shared__ unsigned s3m[32];
  int b = blockIdx.x;
  int tid = threadIdx.x;
  int oc = tid >> 2, part = tid & 3;  // 4 adjacent lanes share one oc

  // s2 layout [b][j][oc]; part p covers j in [jstart, jstart+jcount)
  int jstart = (part == 0) ? 0 : 33 + (part - 1) * 32;
  int jcount = (part == 0) ? 33 : 32;
  const unsigned short* base = s2 + (size_t)b * S2R * 64 + oc;
  int cnt[16];
#pragma unroll
  for (int t = 0; t < 16; ++t) cnt[t] = 0;
  for (int u = 0; u < jcount; ++u) {
    unsigned m = base[(size_t)(jstart + u) * 64];
#pragma unroll
    for (int t = 0; t < 16; ++t) cnt[t] += (int)((m >> t) & 1u);
  }
#pragma unroll
  for (int t = 0; t < 16; ++t) {
    cnt[t] += __shfl_xor(cnt[t], 1);
    cnt[t] += __shfl_xor(cnt[t], 2);
  }
  if (part == 0) {
#pragma unroll
    for (int t = 0; t < 16; ++t) meanL[t][oc] = (float)cnt[t] / 129.f;
  }
  __syncthreads();

  if (tid < 32) {
    int o = tid;
    const float* wrow = fc1w + o * 64;
    float bb = fc1b[o];
    float v = 0.f;
    unsigned msk = 0;
    for (int t = 0; t < 16; ++t) {
      float s = 0.f;
      for (int d = 0; d < 64; ++d) s = fmaf(meanL[t][d], wrow[d], s);
      float xin = s + bb;
      v = v + (xin - v) * 0.5f;
      if (v >= 1.f) { msk |= (1u << t); v = 0.f; }
    }
    s3m[o] = msk;
  }
  __syncthreads();

  if (tid < 5) {
    int q = tid;
    const float* wrow = fc2w + q * 32;
    float bb = fc2b[q];
    float accs = 0.f;
    for (int t = 0; t < 16; ++t) {
      float s = 0.f;
      for (int o = 0; o < 32; ++o) s += (((s3m[o] >> t) & 1u) ? wrow[o] : 0.f);
      accs += (s + bb);
    }
    out[b * 5 + q] = accs / 16.f;
  }
}

extern "C" void kernel_launch(void* const* d_in, const int* in_sizes, int n_in,
                              void* d_out, int out_size, void* d_ws, size_t ws_size,
                              hipStream_t stream) {
  const float* x   = (const float*)d_in[0];
  const float* w0  = (const float*)d_in[1];
  const float* b0  = (const float*)d_in[2];
  const float* bng = (const float*)d_in[3];
  const float* bnb = (const float*)d_in[4];
  const float* bnm = (const float*)d_in[5];
  const float* bnv = (const float*)d_in[6];
  const float* w1  = (const float*)d_in[7];
  const float* b1  = (const float*)d_in[8];
  const float* w2  = (const float*)d_in[9];
  const float* b2  = (const float*)d_in[10];
  const float* f1w = (const float*)d_in[11];
  const float* f1b = (const float*)d_in[12];
  const float* f2w = (const float*)d_in[13];
  const float* f2b = (const float*)d_in[14];
  float* out = (float*)d_out;

  char* ws = (char*)d_ws;
  size_t sz_h  = (size_t)NB * 16 * LP * 4;       // 16,793,600
  size_t sz_m1 = (size_t)NB * 32 * M1S * 2;      //  8,519,680
  size_t sz_s2 = (size_t)NB * S2R * 64 * 2;      //  4,325,376
  size_t off_m1 = sz_h;
  size_t off_s2 = off_m1 + sz_m1;
  size_t off_sm = off_s2 + sz_s2;
  size_t sz_sm = (2560 + 6144) * 4;
  if (ws_size < off_sm + sz_sm) return;          // ~29.7 MB needed

  float* h = (float*)ws;
  unsigned short* m1 = (unsigned short*)(ws + off_m1);
  unsigned short* s2 = (unsigned short*)(ws + off_s2);
  float* w1t = (float*)(ws + off_sm);
  float* w2t = w1t + 2560;

  kA_conv0<<<NB * 5, 256, 0, stream>>>(x, w0, b0, bng, bnb, bnm, bnv, h, w1, w2, w1t, w2t);
  kB_conv1_lif<<<NB * 5, 256, 0, stream>>>(h, w1t, b1, m1);
  kD_conv2_lif<<<NB * 33, 256, 0, stream>>>(m1, w2t, b2, s2);
  kE_head<<<NB, 256, 0, stream>>>(s2, f1w, f1b, f2w, f2b, out);
}

// Round 7
// 121.102 us; speedup vs baseline: 3.7763x; 1.0865x over previous
//
#include <hip/hip_runtime.h>
#include <math.h>

// HybridSNN: time-collapsed spiking CNN (exact fp32 replication, bit-exact orders).
//  kF: conv0+BN+ReLU+maxpool (h tile kept in LDS) + conv1 + 16-step LIF -> m1
//      [256][32][520] u16 bitmask over t. (+w2 transpose tail in blocks 0..15)
//  kD: maxpool(OR) + conv2 over bits + LIF2 -> s2 [256][132][64] u16 ([b][j][oc])
//      wave = 1 j, lanes = 64 oc; ballot-compacted nonzero-c loop; F rows padded
//      to 80B (conflict-free b128 writes); F reads are wave broadcasts.
//  kE: popcount-mean + fc1 + LIF3 + fc2 -> out [256][5] f32

#define NB 256
#define LX 4097
#define LQ 2049
#define LP 1025
#define LJ1 513
#define LP1 257
#define LJ2 129

#define M1S 520
#define S2R 132
#define HSW 260   // hs row stride (floats)

typedef float f32x4 __attribute__((ext_vector_type(4)));

// ---------------------------------------------------------------- kF ---------
// grid: 256 b x 5 jt. J0 = jt*128. h positions p in [2*J0-2, 2*J0+258].
__global__ __launch_bounds__(256) void kF_front(const float* __restrict__ x,
                                                const float* __restrict__ w0,
                                                const float* __restrict__ b0,
                                                const float* __restrict__ bng,
                                                const float* __restrict__ bnb,
                                                const float* __restrict__ bnm,
                                                const float* __restrict__ bnv,
                                                const float* __restrict__ w1,
                                                const float* __restrict__ b1,
                                                unsigned short* __restrict__ m1,
                                                const float* __restrict__ w2,
                                                float* __restrict__ w2t) {
  __shared__ __align__(16) float xs[1052];      //  4208 B  x window
  __shared__ __align__(16) float hs[16 * HSW];  // 16640 B  h tile
  __shared__ __align__(16) float wl[2560];      // 10240 B  w1 transposed
  __shared__ float w0s[112];
  __shared__ float cpar[64];                    // per c: m, g, bb, bc
  __shared__ float rs_l[16];
  int bid = blockIdx.x;
  int b = bid / 5, jt = bid % 5;
  int J0 = jt * 128;
  int Pstart = 2 * J0 - 2;
  int tid = threadIdx.x;

  // ---- phase 1: stage x window, w1 (transposed), conv0 constants
  if (tid < 16) rs_l[tid] = (float)(1.0 / sqrt((double)bnv[tid] + 1e-5));
  {
    const float* xb = x + (size_t)b * LX;
    int xoff = 4 * Pstart - 5;
    for (int i = tid; i < 1052; i += 256) {
      int gi = xoff + i;
      xs[i] = (gi >= 0 && gi < LX) ? xb[gi] : 0.f;
    }
    for (int i = tid; i < 2560; i += 256) {
      int c = i & 31, r = i >> 5;           // r = ic*5 + k
      wl[i] = w1[c * 80 + r];
    }
    if (tid < 112) w0s[tid] = w0[tid];
    if (tid >= 128 && tid < 192) {
      int i = tid - 128;
      int c = i >> 2, e = i & 3;
      float v = (e == 0) ? bnm[c] : (e == 1) ? bng[c] : (e == 2) ? bnb[c] : b0[c];
      cpar[i] = v;
    }
  }
  __syncthreads();

  // ---- phase 2: conv0 + BN + ReLU + maxpool -> hs[c][dp], p = Pstart+dp
  for (int item = tid; item < 16 * 261; item += 256) {
    int c = item / 261, dp = item - c * 261;
    int p = Pstart + dp;
    float hm = 0.f;
    if (p >= 0 && p < LP) {
      const f32x4* xv = (const f32x4*)(xs + 4 * dp);
      f32x4 a = xv[0], bq = xv[1], cq = xv[2];
      float win[12] = {a.x, a.y, a.z, a.w, bq.x, bq.y, bq.z, bq.w,
                       cq.x, cq.y, cq.z, cq.w};
      float m = cpar[4 * c], g = cpar[4 * c + 1], bb = cpar[4 * c + 2],
            bc = cpar[4 * c + 3];
      float rs = rs_l[c];
      float wv[7];
#pragma unroll
      for (int k = 0; k < 7; ++k) wv[k] = w0s[c * 7 + k];
      float best = -INFINITY;
#pragma unroll
      for (int dq = -1; dq <= 1; ++dq) {
        int q = 2 * p + dq;
        if (q < 0 || q >= LQ) continue;
        float s = 0.f;
        int base = 2 * dq + 2;
#pragma unroll
        for (int k = 0; k < 7; ++k) s = fmaf(win[base + k], wv[k], s);
        float y = s + bc;
        y = (y - m) * rs * g + bb;
        y = fmaxf(y, 0.f);
        best = fmaxf(best, y);
      }
      hm = best;
    }
    hs[c * HSW + dp] = hm;
  }
  __syncthreads();

  // ---- phase 3: conv1 + 16-step LIF (const input) -> m1
  {
    int c = tid & 31, jg = tid >> 5;
    int jbase = J0 + jg * 16;
    if (jbase <= 512) {
      float acc[16];
#pragma unroll
      for (int i = 0; i < 16; ++i) acc[i] = 0.f;

      for (int ic = 0; ic < 16; ++ic) {
        float win[36];
        const f32x4* row = (const f32x4*)(hs + ic * HSW + 32 * jg);
#pragma unroll
        for (int i = 0; i < 9; ++i) {
          f32x4 v = row[i];
          win[4 * i] = v.x; win[4 * i + 1] = v.y;
          win[4 * i + 2] = v.z; win[4 * i + 3] = v.w;
        }
        float wv[5];
#pragma unroll
        for (int k = 0; k < 5; ++k) wv[k] = wl[(ic * 5 + k) * 32 + c];
#pragma unroll
        for (int j = 0; j < 16; ++j) {
#pragma unroll
          for (int k = 0; k < 5; ++k) acc[j] = fmaf(win[2 * j + k], wv[k], acc[j]);
        }
      }

      float bc = b1[c];
      unsigned mskv[16];
#pragma unroll
      for (int j = 0; j < 16; ++j) {
        float xin = acc[j] + bc;
        float v = 0.f; unsigned mm = 0;
#pragma unroll
        for (int t = 0; t < 16; ++t) {
          v = v + (xin - v) * 0.5f;
          if (v >= 1.f) { mm |= (1u << t); v = 0.f; }
        }
        mskv[j] = mm;
      }
      size_t rowo = ((size_t)b * 32 + c) * M1S + jbase;
      if (jbase + 15 < LJ1) {
        uint4 u0, u1;
        u0.x = mskv[0] | (mskv[1] << 16);
        u0.y = mskv[2] | (mskv[3] << 16);
        u0.z = mskv[4] | (mskv[5] << 16);
        u0.w = mskv[6] | (mskv[7] << 16);
        u1.x = mskv[8] | (mskv[9] << 16);
        u1.y = mskv[10] | (mskv[11] << 16);
        u1.z = mskv[12] | (mskv[13] << 16);
        u1.w = mskv[14] | (mskv[15] << 16);
        *(uint4*)(m1 + rowo) = u0;
        *(uint4*)(m1 + rowo + 8) = u1;
      } else {
        for (int j = 0; j < 16; ++j)
          if (jbase + j < LJ1) m1[rowo + j] = (unsigned short)mskv[j];
      }
    }
  }

  // ---- tail: w2 transpose (blocks 0..15), independent of LDS phases
  if (bid < 16) {
    for (int idx = bid * 256 + tid; idx < 64 * 32 * 3; idx += 4096) {
      int k = idx % 3; int r = idx / 3; int c = r % 32; int oc = r / 32;
      w2t[(c * 3 + k) * 64 + oc] = w2[idx];
    }
  }
}

// ---------------------------------------------------------------- kD ---------
// grid: 256 b x 33 jt; block 4 waves; wave w -> j = jt*4+w; lane = oc.
__global__ __launch_bounds__(256) void kD_conv2_lif(const unsigned short* __restrict__ m1,
                                                    const float* __restrict__ w2t_g,
                                                    const float* __restrict__ b2,
                                                    unsigned short* __restrict__ s2) {
  __shared__ __align__(16) float F[288 * 20];     // 23040 B, 80B rows (conflict-free)
  __shared__ unsigned mval[288];                  //  1152 B
  __shared__ unsigned short mbuf[32 * 20];        //  1280 B
  int bid = blockIdx.x;
  int b = bid / 33, jt = bid % 33;
  int j0 = jt * 4;
  int tid = threadIdx.x;
  int w = tid >> 6;      // wave id = j offset
  int lane = tid & 63;   // oc

  // stage m1 window: q = 4*j0 - 3 + u, u in [0,20)
  const unsigned short* m1b = m1 + (size_t)b * 32 * M1S;
  int qbase = 4 * j0 - 3;
  for (int i = tid; i < 1024; i += 256) {
    int c = i >> 5, u = i & 31;
    if (u < 20) {
      int q = qbase + u;
      mbuf[c * 20 + u] = (q >= 0 && q <= 512) ? m1b[(size_t)c * M1S + q] : (unsigned short)0;
    }
  }
  __syncthreads();

  // build F rows + mval: 288 = 32 c x 9 positions (maxpool-OR folded)
  for (int it = tid; it < 288; it += 256) {
    int c = it / 9, idx = it - c * 9;
    int p = 2 * j0 - 1 + idx;
    unsigned m = 0;
    if (p >= 0 && p < LP1) {
      const unsigned short* mr = mbuf + c * 20;
      int l0 = 2 * idx;
      m = (unsigned)mr[l0] | (unsigned)mr[l0 + 1] | (unsigned)mr[l0 + 2];
    }
    mval[it] = m;
    f32x4* Fr = (f32x4*)(F + it * 20);
    f32x4 f0, f1, f2, f3;
    f0.x = (float)(m & 1u);         f0.y = (float)((m >> 1) & 1u);
    f0.z = (float)((m >> 2) & 1u);  f0.w = (float)((m >> 3) & 1u);
    f1.x = (float)((m >> 4) & 1u);  f1.y = (float)((m >> 5) & 1u);
    f1.z = (float)((m >> 6) & 1u);  f1.w = (float)((m >> 7) & 1u);
    f2.x = (float)((m >> 8) & 1u);  f2.y = (float)((m >> 9) & 1u);
    f2.z = (float)((m >> 10) & 1u); f2.w = (float)((m >> 11) & 1u);
    f3.x = (float)((m >> 12) & 1u); f3.y = (float)((m >> 13) & 1u);
    f3.z = (float)((m >> 14) & 1u); f3.w = (float)((m >> 15) & 1u);
    Fr[0] = f0; Fr[1] = f1; Fr[2] = f2; Fr[3] = f3;
  }
  __syncthreads();

  // ballot-compact the nonzero channels for this wave's j
  unsigned bits;
  {
    bool nz = false;
    if (lane < 32) {
      int base9 = lane * 9 + 2 * w;
      nz = (mval[base9] | mval[base9 + 1] | mval[base9 + 2]) != 0u;
    }
    bits = (unsigned)__ballot(nz);
  }

  float acc[16];
#pragma unroll
  for (int t = 0; t < 16; ++t) acc[t] = 0.f;

  const float* wrow = w2t_g + lane;  // w2t[(c*3+k)*64 + oc], coalesced, L1/L2
  while (bits) {
    int c = __builtin_ctz(bits);
    bits &= bits - 1;
    int base9 = c * 9 + 2 * w;
    unsigned mv0 = mval[base9];
    unsigned mv1 = mval[base9 + 1];
    unsigned mv2 = mval[base9 + 2];
    const float* wr = wrow + c * 192;
    const float* Fb = F + base9 * 20;
    if (mv0) {
      float wv = wr[0];
      const f32x4* Fp = (const f32x4*)Fb;
      f32x4 fv[4];
      fv[0] = Fp[0]; fv[1] = Fp[1]; fv[2] = Fp[2]; fv[3] = Fp[3];
#pragma unroll
      for (int t = 0; t < 16; ++t) acc[t] = fmaf(wv, fv[t >> 2][t & 3], acc[t]);
    }
    if (mv1) {
      float wv = wr[64];
      const f32x4* Fp = (const f32x4*)(Fb + 20);
      f32x4 fv[4];
      fv[0] = Fp[0]; fv[1] = Fp[1]; fv[2] = Fp[2]; fv[3] = Fp[3];
#pragma unroll
      for (int t = 0; t < 16; ++t) acc[t] = fmaf(wv, fv[t >> 2][t & 3], acc[t]);
    }
    if (mv2) {
      float wv = wr[128];
      const f32x4* Fp = (const f32x4*)(Fb + 40);
      f32x4 fv[4];
      fv[0] = Fp[0]; fv[1] = Fp[1]; fv[2] = Fp[2]; fv[3] = Fp[3];
#pragma unroll
      for (int t = 0; t < 16; ++t) acc[t] = fmaf(wv, fv[t >> 2][t & 3], acc[t]);
    }
  }

  int j = j0 + w;
  if (j < LJ2) {
    float bc = b2[lane];
    float v = 0.f; unsigned mm = 0;
#pragma unroll
    for (int t = 0; t < 16; ++t) {
      float xin = acc[t] + bc;
      v = v + (xin - v) * 0.5f;
      if (v >= 1.f) { mm |= (1u << t); v = 0.f; }
    }
    s2[((size_t)b * S2R + j) * 64 + lane] = (unsigned short)mm;  // coalesced
  }
}

// ---------------------------------------------------------------- kE ---------
__global__ __launch_bounds__(256) void kE_head(const unsigned short* __restrict__ s2,
                                               const float* __restrict__ fc1w,
                                               const float* __restrict__ fc1b,
                                               const float* __restrict__ fc2w,
                                               const float* __restrict__ fc2b,
                                               float* __restrict__ out) {
  __shared__ float meanL[16][64];
  __shared__ unsigned s3m[32];
  int b = blockIdx.x;
  int tid = threadIdx.x;
  int oc = tid >> 2, part = tid & 3;

  int jstart = (part == 0) ? 0 : 33 + (part - 1) * 32;
  int jcount = (part == 0) ? 33 : 32;
  const unsigned short* base = s2 + (size_t)b * S2R * 64 + oc;
  int cnt[16];
#pragma unroll
  for (int t = 0; t < 16; ++t) cnt[t] = 0;
  for (int u = 0; u < jcount; ++u) {
    unsigned m = base[(size_t)(jstart + u) * 64];
#pragma unroll
    for (int t = 0; t < 16; ++t) cnt[t] += (int)((m >> t) & 1u);
  }
#pragma unroll
  for (int t = 0; t < 16; ++t) {
    cnt[t] += __shfl_xor(cnt[t], 1);
    cnt[t] += __shfl_xor(cnt[t], 2);
  }
  if (part == 0) {
#pragma unroll
    for (int t = 0; t < 16; ++t) meanL[t][oc] = (float)cnt[t] / 129.f;
  }
  __syncthreads();

  if (tid < 32) {
    int o = tid;
    const float* wrow = fc1w + o * 64;
    float bb = fc1b[o];
    float v = 0.f;
    unsigned msk = 0;
    for (int t = 0; t < 16; ++t) {
      float s = 0.f;
      for (int d = 0; d < 64; ++d) s = fmaf(meanL[t][d], wrow[d], s);
      float xin = s + bb;
      v = v + (xin - v) * 0.5f;
      if (v >= 1.f) { msk |= (1u << t); v = 0.f; }
    }
    s3m[o] = msk;
  }
  __syncthreads();

  if (tid < 5) {
    int q = tid;
    const float* wrow = fc2w + q * 32;
    float bb = fc2b[q];
    float accs = 0.f;
    for (int t = 0; t < 16; ++t) {
      float s = 0.f;
      for (int o = 0; o < 32; ++o) s += (((s3m[o] >> t) & 1u) ? wrow[o] : 0.f);
      accs += (s + bb);
    }
    out[b * 5 + q] = accs / 16.f;
  }
}

extern "C" void kernel_launch(void* const* d_in, const int* in_sizes, int n_in,
                              void* d_out, int out_size, void* d_ws, size_t ws_size,
                              hipStream_t stream) {
  const float* x   = (const float*)d_in[0];
  const float* w0  = (const float*)d_in[1];
  const float* b0  = (const float*)d_in[2];
  const float* bng = (const float*)d_in[3];
  const float* bnb = (const float*)d_in[4];
  const float* bnm = (const float*)d_in[5];
  const float* bnv = (const float*)d_in[6];
  const float* w1  = (const float*)d_in[7];
  const float* b1  = (const float*)d_in[8];
  const float* w2  = (const float*)d_in[9];
  const float* b2  = (const float*)d_in[10];
  const float* f1w = (const float*)d_in[11];
  const float* f1b = (const float*)d_in[12];
  const float* f2w = (const float*)d_in[13];
  const float* f2b = (const float*)d_in[14];
  float* out = (float*)d_out;

  char* ws = (char*)d_ws;
  size_t sz_m1 = (size_t)NB * 32 * M1S * 2;      // 8,519,680
  size_t sz_s2 = (size_t)NB * S2R * 64 * 2;      // 4,325,376
  size_t off_s2 = sz_m1;
  size_t off_w2 = off_s2 + sz_s2;
  if (ws_size < off_w2 + 6144 * 4) return;       // ~12.9 MB needed

  unsigned short* m1 = (unsigned short*)ws;
  unsigned short* s2 = (unsigned short*)(ws + off_s2);
  float* w2t = (float*)(ws + off_w2);

  kF_front<<<NB * 5, 256, 0, stream>>>(x, w0, b0, bng, bnb, bnm, bnv, w1, b1, m1, w2, w2t);
  kD_conv2_lif<<<NB * 33, 256, 0, stream>>>(m1, w2t, b2, s2);
  kE_head<<<NB, 256, 0, stream>>>(s2, f1w, f1b, f2w, f2b, out);
}

// Round 8
// 121.047 us; speedup vs baseline: 3.7780x; 1.0005x over previous
//
#include <hip/hip_runtime.h>
#include <math.h>

// HybridSNN: time-collapsed spiking CNN (exact fp32 replication, bit-exact orders).
//  kF: conv0+BN+ReLU+maxpool (h tile in LDS) + conv1 + 16-step LIF -> m1
//      [256][32][520] u16 bitmask over t. (+w2 transpose tail in blocks 0..15)
//  kD: maxpool(OR) + conv2 over bits + LIF2 -> s2 [256][132][64] u16 ([b][j][oc])
//      128-thr block, 4 j; wave = 2 j (half-wave each) x 2 oc/lane -> 12 b128
//      feed 96 FMA (FMA-bound); ballot-compacted nonzero-c loop.
//  kE: popcount-mean + fc1 + LIF3 + fc2 -> out [256][5] f32 (lane=oc, coalesced)

#define NB 256
#define LX 4097
#define LQ 2049
#define LP 1025
#define LJ1 513
#define LP1 257
#define LJ2 129

#define M1S 520
#define S2R 132
#define HSW 260   // hs row stride (floats)

typedef float f32x4 __attribute__((ext_vector_type(4)));

// ---------------------------------------------------------------- kF ---------
// grid: 256 b x 5 jt. J0 = jt*128. h positions p in [2*J0-2, 2*J0+258].
__global__ __launch_bounds__(256) void kF_front(const float* __restrict__ x,
                                                const float* __restrict__ w0,
                                                const float* __restrict__ b0,
                                                const float* __restrict__ bng,
                                                const float* __restrict__ bnb,
                                                const float* __restrict__ bnm,
                                                const float* __restrict__ bnv,
                                                const float* __restrict__ w1,
                                                const float* __restrict__ b1,
                                                unsigned short* __restrict__ m1,
                                                const float* __restrict__ w2,
                                                float* __restrict__ w2t) {
  __shared__ __align__(16) float xs[1052];      //  4208 B  x window
  __shared__ __align__(16) float hs[16 * HSW];  // 16640 B  h tile
  __shared__ __align__(16) float wl[2560];      // 10240 B  w1 transposed
  __shared__ float w0s[112];
  __shared__ float cpar[64];                    // per c: m, g, bb, bc
  __shared__ float rs_l[16];
  int bid = blockIdx.x;
  int b = bid / 5, jt = bid % 5;
  int J0 = jt * 128;
  int Pstart = 2 * J0 - 2;
  int tid = threadIdx.x;

  // ---- phase 1: stage x window, w1 (transposed), conv0 constants
  if (tid < 16) rs_l[tid] = (float)(1.0 / sqrt((double)bnv[tid] + 1e-5));
  {
    const float* xb = x + (size_t)b * LX;
    int xoff = 4 * Pstart - 5;
    for (int i = tid; i < 1052; i += 256) {
      int gi = xoff + i;
      xs[i] = (gi >= 0 && gi < LX) ? xb[gi] : 0.f;
    }
    for (int i = tid; i < 2560; i += 256) {
      int c = i & 31, r = i >> 5;           // r = ic*5 + k
      wl[i] = w1[c * 80 + r];
    }
    if (tid < 112) w0s[tid] = w0[tid];
    if (tid >= 128 && tid < 192) {
      int i = tid - 128;
      int c = i >> 2, e = i & 3;
      float v = (e == 0) ? bnm[c] : (e == 1) ? bng[c] : (e == 2) ? bnb[c] : b0[c];
      cpar[i] = v;
    }
  }
  __syncthreads();

  // ---- phase 2: conv0 + BN + ReLU + maxpool -> hs[c][dp], p = Pstart+dp
  // thread = (c2 = tid>>4, g2 = tid&15); per-c constants hoisted out of the loop
  {
    int c2 = tid >> 4, g2 = tid & 15;
    float m = cpar[4 * c2], g = cpar[4 * c2 + 1], bb = cpar[4 * c2 + 2],
          bc = cpar[4 * c2 + 3];
    float rs = rs_l[c2];
    float wv[7];
#pragma unroll
    for (int k = 0; k < 7; ++k) wv[k] = w0s[c2 * 7 + k];
#pragma unroll
    for (int i = 0; i < 17; ++i) {
      int dp = g2 * 17 + i;
      if (dp >= 261) break;
      int p = Pstart + dp;
      float hm = 0.f;
      if (p >= 0 && p < LP) {
        const f32x4* xv = (const f32x4*)(xs + 4 * dp);
        f32x4 a = xv[0], bq = xv[1], cq = xv[2];
        float win[12] = {a.x, a.y, a.z, a.w, bq.x, bq.y, bq.z, bq.w,
                         cq.x, cq.y, cq.z, cq.w};
        float best = -INFINITY;
#pragma unroll
        for (int dq = -1; dq <= 1; ++dq) {
          int q = 2 * p + dq;
          if (q < 0 || q >= LQ) continue;
          float s = 0.f;
          int base = 2 * dq + 2;
#pragma unroll
          for (int k = 0; k < 7; ++k) s = fmaf(win[base + k], wv[k], s);
          float y = s + bc;
          y = (y - m) * rs * g + bb;
          y = fmaxf(y, 0.f);
          best = fmaxf(best, y);
        }
        hm = best;
      }
      hs[c2 * HSW + dp] = hm;
    }
  }
  __syncthreads();

  // ---- phase 3: conv1 + 16-step LIF (const input) -> m1
  {
    int c = tid & 31, jg = tid >> 5;
    int jbase = J0 + jg * 16;
    if (jbase <= 512) {
      float acc[16];
#pragma unroll
      for (int i = 0; i < 16; ++i) acc[i] = 0.f;

      for (int ic = 0; ic < 16; ++ic) {
        float win[36];
        const f32x4* row = (const f32x4*)(hs + ic * HSW + 32 * jg);
#pragma unroll
        for (int i = 0; i < 9; ++i) {
          f32x4 v = row[i];
          win[4 * i] = v.x; win[4 * i + 1] = v.y;
          win[4 * i + 2] = v.z; win[4 * i + 3] = v.w;
        }
        float wv[5];
#pragma unroll
        for (int k = 0; k < 5; ++k) wv[k] = wl[(ic * 5 + k) * 32 + c];
#pragma unroll
        for (int j = 0; j < 16; ++j) {
#pragma unroll
          for (int k = 0; k < 5; ++k) acc[j] = fmaf(win[2 * j + k], wv[k], acc[j]);
        }
      }

      float bc = b1[c];
      unsigned mskv[16];
#pragma unroll
      for (int j = 0; j < 16; ++j) {
        float xin = acc[j] + bc;
        float v = 0.f; unsigned mm = 0;
#pragma unroll
        for (int t = 0; t < 16; ++t) {
          v = v + (xin - v) * 0.5f;
          if (v >= 1.f) { mm |= (1u << t); v = 0.f; }
        }
        mskv[j] = mm;
      }
      size_t rowo = ((size_t)b * 32 + c) * M1S + jbase;
      if (jbase + 15 < LJ1) {
        uint4 u0, u1;
        u0.x = mskv[0] | (mskv[1] << 16);
        u0.y = mskv[2] | (mskv[3] << 16);
        u0.z = mskv[4] | (mskv[5] << 16);
        u0.w = mskv[6] | (mskv[7] << 16);
        u1.x = mskv[8] | (mskv[9] << 16);
        u1.y = mskv[10] | (mskv[11] << 16);
        u1.z = mskv[12] | (mskv[13] << 16);
        u1.w = mskv[14] | (mskv[15] << 16);
        *(uint4*)(m1 + rowo) = u0;
        *(uint4*)(m1 + rowo + 8) = u1;
      } else {
        for (int j = 0; j < 16; ++j)
          if (jbase + j < LJ1) m1[rowo + j] = (unsigned short)mskv[j];
      }
    }
  }

  // ---- tail: w2 transpose (blocks 0..15)
  if (bid < 16) {
    for (int idx = bid * 256 + tid; idx < 64 * 32 * 3; idx += 4096) {
      int k = idx % 3; int r = idx / 3; int c = r % 32; int oc = r / 32;
      w2t[(c * 3 + k) * 64 + oc] = w2[idx];
    }
  }
}

// ---------------------------------------------------------------- kD ---------
// grid: 256 b x 33 jt; block 128 thr = 2 waves; wave w covers j = J0+2w+{0,1}
// (half-wave each); lane: oc0 = lane&31, oc1 = oc0+32. acc[2 oc][16 t].
__global__ __launch_bounds__(128) void kD_conv2_lif(const unsigned short* __restrict__ m1,
                                                    const float* __restrict__ w2t_g,
                                                    const float* __restrict__ b2,
                                                    unsigned short* __restrict__ s2) {
  __shared__ __align__(16) float F[288 * 20];     // 23040 B, 80B rows
  __shared__ unsigned mval[288];                  //  1152 B
  __shared__ unsigned short mbuf[32 * 20];        //  1280 B
  int bid = blockIdx.x;
  int b = bid / 33, jt = bid % 33;
  int J0 = jt * 4;
  int tid = threadIdx.x;
  int w = tid >> 6;        // wave id (0..1)
  int lane = tid & 63;
  int wh = lane >> 5;      // half-wave -> j = J0 + 2w + wh
  int oc0 = lane & 31;

  // stage m1 window: q = 4*J0 - 3 + u, u in [0,19)
  const unsigned short* m1b = m1 + (size_t)b * 32 * M1S;
  int qbase = 4 * J0 - 3;
  for (int i = tid; i < 640; i += 128) {
    int c = i / 20, u = i - c * 20;
    if (u < 19) {
      int q = qbase + u;
      mbuf[c * 20 + u] = (q >= 0 && q <= 512) ? m1b[(size_t)c * M1S + q] : (unsigned short)0;
    }
  }
  __syncthreads();

  // build F rows + mval: 288 = 32 c x 9 positions (maxpool-OR folded)
  for (int it = tid; it < 288; it += 128) {
    int c = it / 9, idx = it - c * 9;
    int p = 2 * J0 - 1 + idx;
    unsigned m = 0;
    if (p >= 0 && p < LP1) {
      const unsigned short* mr = mbuf + c * 20;
      int l0 = 2 * idx;
      m = (unsigned)mr[l0] | (unsigned)mr[l0 + 1] | (unsigned)mr[l0 + 2];
    }
    mval[it] = m;
    f32x4* Fr = (f32x4*)(F + it * 20);
    f32x4 f0, f1, f2, f3;
    f0.x = (float)(m & 1u);         f0.y = (float)((m >> 1) & 1u);
    f0.z = (float)((m >> 2) & 1u);  f0.w = (float)((m >> 3) & 1u);
    f1.x = (float)((m >> 4) & 1u);  f1.y = (float)((m >> 5) & 1u);
    f1.z = (float)((m >> 6) & 1u);  f1.w = (float)((m >> 7) & 1u);
    f2.x = (float)((m >> 8) & 1u);  f2.y = (float)((m >> 9) & 1u);
    f2.z = (float)((m >> 10) & 1u); f2.w = (float)((m >> 11) & 1u);
    f3.x = (float)((m >> 12) & 1u); f3.y = (float)((m >> 13) & 1u);
    f3.z = (float)((m >> 14) & 1u); f3.w = (float)((m >> 15) & 1u);
    Fr[0] = f0; Fr[1] = f1; Fr[2] = f2; Fr[3] = f3;
  }
  __syncthreads();

  // ballot-compact nonzero c over the wave's 5-position window lp = 4w..4w+4
  unsigned bits;
  {
    bool nz = false;
    if (lane < 32) {
      int mb = lane * 9 + 4 * w;
      unsigned o = mval[mb] | mval[mb + 1] | mval[mb + 2] | mval[mb + 3] | mval[mb + 4];
      nz = (o != 0u);
    }
    bits = (unsigned)__ballot(nz);
  }

  float acc0[16], acc1[16];
#pragma unroll
  for (int t = 0; t < 16; ++t) { acc0[t] = 0.f; acc1[t] = 0.f; }

  int lp0 = 4 * w + 2 * wh;                 // this half's k=0 position
  const float* Fbase = F + lp0 * 20;        // + c*180
  const float* wbase = w2t_g + oc0;         // + c*192 + 64k (+32 for oc1)

  while (bits) {
    int c = __builtin_ctz(bits);
    bits &= bits - 1;
    const float* wr = wbase + c * 192;
    float wa0 = wr[0],  wb0 = wr[64], wc0 = wr[128];
    float wa1 = wr[32], wb1 = wr[96], wc1 = wr[160];
    const f32x4* Fp = (const f32x4*)(Fbase + c * 180);
    f32x4 ra0 = Fp[0],  ra1 = Fp[1],  ra2 = Fp[2],  ra3 = Fp[3];   // k=0 row
    f32x4 rb0 = Fp[5],  rb1 = Fp[6],  rb2 = Fp[7],  rb3 = Fp[8];   // k=1 row
    f32x4 rc0 = Fp[10], rc1 = Fp[11], rc2 = Fp[12], rc3 = Fp[13];  // k=2 row
    float fa[16] = {ra0.x, ra0.y, ra0.z, ra0.w, ra1.x, ra1.y, ra1.z, ra1.w,
                    ra2.x, ra2.y, ra2.z, ra2.w, ra3.x, ra3.y, ra3.z, ra3.w};
    float fb[16] = {rb0.x, rb0.y, rb0.z, rb0.w, rb1.x, rb1.y, rb1.z, rb1.w,
                    rb2.x, rb2.y, rb2.z, rb2.w, rb3.x, rb3.y, rb3.z, rb3.w};
    float fc[16] = {rc0.x, rc0.y, rc0.z, rc0.w, rc1.x, rc1.y, rc1.z, rc1.w,
                    rc2.x, rc2.y, rc2.z, rc2.w, rc3.x, rc3.y, rc3.z, rc3.w};
#pragma unroll
    for (int t = 0; t < 16; ++t) {
      acc0[t] = fmaf(wa0, fa[t], acc0[t]);
      acc1[t] = fmaf(wa1, fa[t], acc1[t]);
    }
#pragma unroll
    for (int t = 0; t < 16; ++t) {
      acc0[t] = fmaf(wb0, fb[t], acc0[t]);
      acc1[t] = fmaf(wb1, fb[t], acc1[t]);
    }
#pragma unroll
    for (int t = 0; t < 16; ++t) {
      acc0[t] = fmaf(wc0, fc[t], acc0[t]);
      acc1[t] = fmaf(wc1, fc[t], acc1[t]);
    }
  }

  int j = J0 + 2 * w + wh;
  if (j < LJ2) {
    unsigned short* srow = s2 + ((size_t)b * S2R + j) * 64;
    {
      float bc = b2[oc0];
      float v = 0.f; unsigned mm = 0;
#pragma unroll
      for (int t = 0; t < 16; ++t) {
        float xin = acc0[t] + bc;
        v = v + (xin - v) * 0.5f;
        if (v >= 1.f) { mm |= (1u << t); v = 0.f; }
      }
      srow[oc0] = (unsigned short)mm;
    }
    {
      float bc = b2[oc0 + 32];
      float v = 0.f; unsigned mm = 0;
#pragma unroll
      for (int t = 0; t < 16; ++t) {
        float xin = acc1[t] + bc;
        v = v + (xin - v) * 0.5f;
        if (v >= 1.f) { mm |= (1u << t); v = 0.f; }
      }
      srow[oc0 + 32] = (unsigned short)mm;
    }
  }
}

// ---------------------------------------------------------------- kE ---------
// block = 256 thr per b; wave = j chunk, lane = oc (coalesced 128B rows)
__global__ __launch_bounds__(256) void kE_head(const unsigned short* __restrict__ s2,
                                               const float* __restrict__ fc1w,
                                               const float* __restrict__ fc1b,
                                               const float* __restrict__ fc2w,
                                               const float* __restrict__ fc2b,
                                               float* __restrict__ out) {
  __shared__ unsigned cntL[4][16][64];   // 16 KB
  __shared__ float meanL[16][64];        //  4 KB
  __shared__ unsigned s3m[32];
  int b = blockIdx.x;
  int tid = threadIdx.x;
  int w = tid >> 6, lane = tid & 63;

  int j0 = (w == 0) ? 0 : 33 + 32 * (w - 1);
  int jc = (w == 0) ? 33 : 32;
  const unsigned short* base = s2 + (size_t)b * S2R * 64 + lane;
  unsigned cnt[16];
#pragma unroll
  for (int t = 0; t < 16; ++t) cnt[t] = 0;
  for (int u = 0; u < jc; ++u) {
    unsigned m = base[(size_t)(j0 + u) * 64];
#pragma unroll
    for (int t = 0; t < 16; ++t) cnt[t] += (m >> t) & 1u;
  }
#pragma unroll
  for (int t = 0; t < 16; ++t) cntL[w][t][lane] = cnt[t];
  __syncthreads();

#pragma unroll
  for (int i = 0; i < 4; ++i) {
    int idx = tid + 256 * i;
    int t = idx >> 6, oc = idx & 63;
    unsigned s = cntL[0][t][oc] + cntL[1][t][oc] + cntL[2][t][oc] + cntL[3][t][oc];
    meanL[t][oc] = (float)s / 129.f;
  }
  __syncthreads();

  if (tid < 32) {
    int o = tid;
    const float* wrow = fc1w + o * 64;
    float bb = fc1b[o];
    float v = 0.f;
    unsigned msk = 0;
    for (int t = 0; t < 16; ++t) {
      float s = 0.f;
      for (int d = 0; d < 64; ++d) s = fmaf(meanL[t][d], wrow[d], s);
      float xin = s + bb;
      v = v + (xin - v) * 0.5f;
      if (v >= 1.f) { msk |= (1u << t); v = 0.f; }
    }
    s3m[o] = msk;
  }
  __syncthreads();

  if (tid < 5) {
    int q = tid;
    const float* wrow = fc2w + q * 32;
    float bb = fc2b[q];
    float accs = 0.f;
    for (int t = 0; t < 16; ++t) {
      float s = 0.f;
      for (int o = 0; o < 32; ++o) s += (((s3m[o] >> t) & 1u) ? wrow[o] : 0.f);
      accs += (s + bb);
    }
    out[b * 5 + q] = accs / 16.f;
  }
}

extern "C" void kernel_launch(void* const* d_in, const int* in_sizes, int n_in,
                              void* d_out, int out_size, void* d_ws, size_t ws_size,
                              hipStream_t stream) {
  const float* x   = (const float*)d_in[0];
  const float* w0  = (const float*)d_in[1];
  const float* b0  = (const float*)d_in[2];
  const float* bng = (const float*)d_in[3];
  const float* bnb = (const float*)d_in[4];
  const float* bnm = (const float*)d_in[5];
  const float* bnv = (const float*)d_in[6];
  const float* w1  = (const float*)d_in[7];
  const float* b1  = (const float*)d_in[8];
  const float* w2  = (const float*)d_in[9];
  const float* b2  = (const float*)d_in[10];
  const float* f1w = (const float*)d_in[11];
  const float* f1b = (const float*)d_in[12];
  const float* f2w = (const float*)d_in[13];
  const float* f2b = (const float*)d_in[14];
  float* out = (float*)d_out;

  char* ws = (char*)d_ws;
  size_t sz_m1 = (size_t)NB * 32 * M1S * 2;      // 8,519,680
  size_t sz_s2 = (size_t)NB * S2R * 64 * 2;      // 4,325,376
  size_t off_s2 = sz_m1;
  size_t off_w2 = off_s2 + sz_s2;
  if (ws_size < off_w2 + 6144 * 4) return;       // ~12.9 MB needed

  unsigned short* m1 = (unsigned short*)ws;
  unsigned short* s2 = (unsigned short*)(ws + off_s2);
  float* w2t = (float*)(ws + off_w2);

  kF_front<<<NB * 5, 256, 0, stream>>>(x, w0, b0, bng, bnb, bnm, bnv, w1, b1, m1, w2, w2t);
  kD_conv2_lif<<<NB * 33, 128, 0, stream>>>(m1, w2t, b2, s2);
  kE_head<<<NB, 256, 0, stream>>>(s2, f1w, f1b, f2w, f2b, out);
}

// Round 9
// 116.545 us; speedup vs baseline: 3.9240x; 1.0386x over previous
//
#include <hip/hip_runtime.h>
#include <math.h>

// HybridSNN: time-collapsed spiking CNN (exact fp32 replication, bit-exact orders).
//  kF: conv0+BN+ReLU+maxpool + conv1 + 16-step LIF -> m1 [256][32][520] u16.
//      h tile processed in ic-HALVES (8.3KB hs) for occupancy; acc in regs across
//      barriers. (+w2 repack tail in blocks 0..15 -> w2t2[c][oc][4])
//  kD: maxpool(OR) + conv2 over bits + LIF2 -> s2 [256][132][64] u16 ([b][j][oc])
//      256-thr/4-wave, wave = 1 j, lane = oc; ballot-compacted c-loop + per-k
//      skips; F rows 80B (conflict-free); weights one b128/lane per c.
//  kE: popcount-mean + fc1 + LIF3 + fc2 -> out [256][5] f32 (lane=oc, coalesced)

#define NB 256
#define LX 4097
#define LQ 2049
#define LP 1025
#define LJ1 513
#define LP1 257
#define LJ2 129

#define M1S 520
#define S2R 132
#define HSW 260   // hs row stride (floats)

typedef float f32x4 __attribute__((ext_vector_type(4)));

// ---------------------------------------------------------------- kF ---------
// grid: 256 b x 5 jt. J0 = jt*128. h positions p in [2*J0-2, 2*J0+258].
__global__ __launch_bounds__(256) void kF_front(const float* __restrict__ x,
                                                const float* __restrict__ w0,
                                                const float* __restrict__ b0,
                                                const float* __restrict__ bng,
                                                const float* __restrict__ bnb,
                                                const float* __restrict__ bnm,
                                                const float* __restrict__ bnv,
                                                const float* __restrict__ w1,
                                                const float* __restrict__ b1,
                                                unsigned short* __restrict__ m1,
                                                const float* __restrict__ w2,
                                                float* __restrict__ w2t2) {
  __shared__ __align__(16) float xs[1052];      //  4208 B  x window
  __shared__ __align__(16) float hs[8 * HSW];   //  8320 B  h half-tile (8 ic)
  __shared__ __align__(16) float wl[2560];      // 10240 B  w1 transposed
  __shared__ float w0s[112];
  __shared__ float cpar[64];                    // per c: m, g, bb, bc
  __shared__ float rs_l[16];
  int bid = blockIdx.x;
  int b = bid / 5, jt = bid % 5;
  int J0 = jt * 128;
  int Pstart = 2 * J0 - 2;
  int tid = threadIdx.x;

  // ---- phase 1: stage x window, w1 (transposed), conv0 constants
  if (tid < 16) rs_l[tid] = (float)(1.0 / sqrt((double)bnv[tid] + 1e-5));
  {
    const float* xb = x + (size_t)b * LX;
    int xoff = 4 * Pstart - 5;
    for (int i = tid; i < 1052; i += 256) {
      int gi = xoff + i;
      xs[i] = (gi >= 0 && gi < LX) ? xb[gi] : 0.f;
    }
    for (int i = tid; i < 2560; i += 256) {
      int c = i & 31, r = i >> 5;           // r = ic*5 + k
      wl[i] = w1[c * 80 + r];
    }
    if (tid < 112) w0s[tid] = w0[tid];
    if (tid >= 128 && tid < 192) {
      int i = tid - 128;
      int c = i >> 2, e = i & 3;
      float v = (e == 0) ? bnm[c] : (e == 1) ? bng[c] : (e == 2) ? bnb[c] : b0[c];
      cpar[i] = v;
    }
  }
  __syncthreads();

  int c = tid & 31, jg = tid >> 5;
  int jbase = J0 + jg * 16;
  bool active = (jbase <= 512);
  float acc[16];
#pragma unroll
  for (int i = 0; i < 16; ++i) acc[i] = 0.f;

  for (int half = 0; half < 2; ++half) {
    // ---- phase 2: conv0+BN+ReLU+maxpool for ic = half*8 .. half*8+7
    {
      int c2l = tid >> 5;        // 0..7
      int g2 = tid & 31;
      int cc = half * 8 + c2l;
      float m = cpar[4 * cc], g = cpar[4 * cc + 1], bb = cpar[4 * cc + 2],
            bc = cpar[4 * cc + 3];
      float rs = rs_l[cc];
      float wv[7];
#pragma unroll
      for (int k = 0; k < 7; ++k) wv[k] = w0s[cc * 7 + k];
#pragma unroll
      for (int i = 0; i < 9; ++i) {
        int dp = g2 * 9 + i;
        if (dp < 261) {
          int p = Pstart + dp;
          float hm = 0.f;
          if (p >= 0 && p < LP) {
            const f32x4* xv = (const f32x4*)(xs + 4 * dp);
            f32x4 a = xv[0], bq = xv[1], cq = xv[2];
            float win[12] = {a.x, a.y, a.z, a.w, bq.x, bq.y, bq.z, bq.w,
                             cq.x, cq.y, cq.z, cq.w};
            float best = -INFINITY;
#pragma unroll
            for (int dq = -1; dq <= 1; ++dq) {
              int q = 2 * p + dq;
              if (q < 0 || q >= LQ) continue;
              float s = 0.f;
              int base = 2 * dq + 2;
#pragma unroll
              for (int k = 0; k < 7; ++k) s = fmaf(win[base + k], wv[k], s);
              float y = s + bc;
              y = (y - m) * rs * g + bb;
              y = fmaxf(y, 0.f);
              best = fmaxf(best, y);
            }
            hm = best;
          }
          hs[c2l * HSW + dp] = hm;
        }
      }
    }
    __syncthreads();

    // ---- phase 3: conv1 accumulate over this ic half
    if (active) {
      for (int icl = 0; icl < 8; ++icl) {
        int ic = half * 8 + icl;
        float win[36];
        const f32x4* row = (const f32x4*)(hs + icl * HSW + 32 * jg);
#pragma unroll
        for (int i = 0; i < 9; ++i) {
          f32x4 v = row[i];
          win[4 * i] = v.x; win[4 * i + 1] = v.y;
          win[4 * i + 2] = v.z; win[4 * i + 3] = v.w;
        }
        float wv[5];
#pragma unroll
        for (int k = 0; k < 5; ++k) wv[k] = wl[(ic * 5 + k) * 32 + c];
#pragma unroll
        for (int j = 0; j < 16; ++j) {
#pragma unroll
          for (int k = 0; k < 5; ++k) acc[j] = fmaf(win[2 * j + k], wv[k], acc[j]);
        }
      }
    }
    __syncthreads();   // hs consumed; safe to overwrite in next half
  }

  // ---- LIF + store
  if (active) {
    float bc = b1[c];
    unsigned mskv[16];
#pragma unroll
    for (int j = 0; j < 16; ++j) {
      float xin = acc[j] + bc;
      float v = 0.f; unsigned mm = 0;
#pragma unroll
      for (int t = 0; t < 16; ++t) {
        v = v + (xin - v) * 0.5f;
        if (v >= 1.f) { mm |= (1u << t); v = 0.f; }
      }
      mskv[j] = mm;
    }
    size_t rowo = ((size_t)b * 32 + c) * M1S + jbase;
    if (jbase + 15 < LJ1) {
      uint4 u0, u1;
      u0.x = mskv[0] | (mskv[1] << 16);
      u0.y = mskv[2] | (mskv[3] << 16);
      u0.z = mskv[4] | (mskv[5] << 16);
      u0.w = mskv[6] | (mskv[7] << 16);
      u1.x = mskv[8] | (mskv[9] << 16);
      u1.y = mskv[10] | (mskv[11] << 16);
      u1.z = mskv[12] | (mskv[13] << 16);
      u1.w = mskv[14] | (mskv[15] << 16);
      *(uint4*)(m1 + rowo) = u0;
      *(uint4*)(m1 + rowo + 8) = u1;
    } else {
      for (int j = 0; j < 16; ++j)
        if (jbase + j < LJ1) m1[rowo + j] = (unsigned short)mskv[j];
    }
  }

  // ---- tail: w2 repack -> w2t2[c][oc][4] (blocks 0..15)
  if (bid < 16) {
    for (int idx = bid * 256 + tid; idx < 64 * 32 * 3; idx += 4096) {
      int k = idx % 3; int r = idx / 3; int cc = r % 32; int oc = r / 32;
      w2t2[((size_t)cc * 64 + oc) * 4 + k] = w2[idx];
    }
  }
}

// ---------------------------------------------------------------- kD ---------
// grid: 256 b x 33 jt; block 4 waves; wave w -> j = jt*4+w; lane = oc.
__global__ __launch_bounds__(256) void kD_conv2_lif(const unsigned short* __restrict__ m1,
                                                    const float* __restrict__ w2t2,
                                                    const float* __restrict__ b2,
                                                    unsigned short* __restrict__ s2) {
  __shared__ __align__(16) float F[288 * 20];     // 23040 B, 80B rows (conflict-free)
  __shared__ unsigned mval[288];                  //  1152 B
  __shared__ unsigned short mbuf[32 * 20];        //  1280 B
  int bid = blockIdx.x;
  int b = bid / 33, jt = bid % 33;
  int j0 = jt * 4;
  int tid = threadIdx.x;
  int w = tid >> 6;      // wave id = j offset
  int lane = tid & 63;   // oc

  // stage m1 window: q = 4*j0 - 3 + u, u in [0,20)
  const unsigned short* m1b = m1 + (size_t)b * 32 * M1S;
  int qbase = 4 * j0 - 3;
  for (int i = tid; i < 1024; i += 256) {
    int c = i >> 5, u = i & 31;
    if (u < 20) {
      int q = qbase + u;
      mbuf[c * 20 + u] = (q >= 0 && q <= 512) ? m1b[(size_t)c * M1S + q] : (unsigned short)0;
    }
  }
  __syncthreads();

  // build F rows + mval: 288 = 32 c x 9 positions (maxpool-OR folded)
  for (int it = tid; it < 288; it += 256) {
    int c = it / 9, idx = it - c * 9;
    int p = 2 * j0 - 1 + idx;
    unsigned m = 0;
    if (p >= 0 && p < LP1) {
      const unsigned short* mr = mbuf + c * 20;
      int l0 = 2 * idx;
      m = (unsigned)mr[l0] | (unsigned)mr[l0 + 1] | (unsigned)mr[l0 + 2];
    }
    mval[it] = m;
    f32x4* Fr = (f32x4*)(F + it * 20);
    f32x4 f0, f1, f2, f3;
    f0.x = (float)(m & 1u);         f0.y = (float)((m >> 1) & 1u);
    f0.z = (float)((m >> 2) & 1u);  f0.w = (float)((m >> 3) & 1u);
    f1.x = (float)((m >> 4) & 1u);  f1.y = (float)((m >> 5) & 1u);
    f1.z = (float)((m >> 6) & 1u);  f1.w = (float)((m >> 7) & 1u);
    f2.x = (float)((m >> 8) & 1u);  f2.y = (float)((m >> 9) & 1u);
    f2.z = (float)((m >> 10) & 1u); f2.w = (float)((m >> 11) & 1u);
    f3.x = (float)((m >> 12) & 1u); f3.y = (float)((m >> 13) & 1u);
    f3.z = (float)((m >> 14) & 1u); f3.w = (float)((m >> 15) & 1u);
    Fr[0] = f0; Fr[1] = f1; Fr[2] = f2; Fr[3] = f3;
  }
  __syncthreads();

  // ballot-compact nonzero channels for this wave's j (3-position window)
  unsigned bits;
  {
    bool nz = false;
    if (lane < 32) {
      int base9 = lane * 9 + 2 * w;
      nz = (mval[base9] | mval[base9 + 1] | mval[base9 + 2]) != 0u;
    }
    bits = (unsigned)__ballot(nz);
  }

  float acc[16];
#pragma unroll
  for (int t = 0; t < 16; ++t) acc[t] = 0.f;

  const f32x4* wbase = (const f32x4*)w2t2 + lane;  // + c*64 -> [c][oc][4]
  while (bits) {
    int c = __builtin_ctz(bits);
    bits &= bits - 1;
    int base9 = c * 9 + 2 * w;
    unsigned mv0 = mval[base9];
    unsigned mv1 = mval[base9 + 1];
    unsigned mv2 = mval[base9 + 2];
    f32x4 wq = wbase[c * 64];          // one coalesced b128: w[k=0..2] (+pad)
    const float* Fb = F + base9 * 20;
    if (mv0) {
      const f32x4* Fp = (const f32x4*)Fb;
      f32x4 fv[4];
      fv[0] = Fp[0]; fv[1] = Fp[1]; fv[2] = Fp[2]; fv[3] = Fp[3];
#pragma unroll
      for (int t = 0; t < 16; ++t) acc[t] = fmaf(wq.x, fv[t >> 2][t & 3], acc[t]);
    }
    if (mv1) {
      const f32x4* Fp = (const f32x4*)(Fb + 20);
      f32x4 fv[4];
      fv[0] = Fp[0]; fv[1] = Fp[1]; fv[2] = Fp[2]; fv[3] = Fp[3];
#pragma unroll
      for (int t = 0; t < 16; ++t) acc[t] = fmaf(wq.y, fv[t >> 2][t & 3], acc[t]);
    }
    if (mv2) {
      const f32x4* Fp = (const f32x4*)(Fb + 40);
      f32x4 fv[4];
      fv[0] = Fp[0]; fv[1] = Fp[1]; fv[2] = Fp[2]; fv[3] = Fp[3];
#pragma unroll
      for (int t = 0; t < 16; ++t) acc[t] = fmaf(wq.z, fv[t >> 2][t & 3], acc[t]);
    }
  }

  int j = j0 + w;
  if (j < LJ2) {
    float bc = b2[lane];
    float v = 0.f; unsigned mm = 0;
#pragma unroll
    for (int t = 0; t < 16; ++t) {
      float xin = acc[t] + bc;
      v = v + (xin - v) * 0.5f;
      if (v >= 1.f) { mm |= (1u << t); v = 0.f; }
    }
    s2[((size_t)b * S2R + j) * 64 + lane] = (unsigned short)mm;  // coalesced
  }
}

// ---------------------------------------------------------------- kE ---------
// block = 256 thr per b; wave = j chunk, lane = oc (coalesced 128B rows)
__global__ __launch_bounds__(256) void kE_head(const unsigned short* __restrict__ s2,
                                               const float* __restrict__ fc1w,
                                               const float* __restrict__ fc1b,
                                               const float* __restrict__ fc2w,
                                               const float* __restrict__ fc2b,
                                               float* __restrict__ out) {
  __shared__ unsigned cntL[4][16][64];   // 16 KB
  __shared__ float meanL[16][64];        //  4 KB
  __shared__ unsigned s3m[32];
  int b = blockIdx.x;
  int tid = threadIdx.x;
  int w = tid >> 6, lane = tid & 63;

  int j0 = (w == 0) ? 0 : 33 + 32 * (w - 1);
  int jc = (w == 0) ? 33 : 32;
  const unsigned short* base = s2 + (size_t)b * S2R * 64 + lane;
  unsigned cnt[16];
#pragma unroll
  for (int t = 0; t < 16; ++t) cnt[t] = 0;
  for (int u = 0; u < jc; ++u) {
    unsigned m = base[(size_t)(j0 + u) * 64];
#pragma unroll
    for (int t = 0; t < 16; ++t) cnt[t] += (m >> t) & 1u;
  }
#pragma unroll
  for (int t = 0; t < 16; ++t) cntL[w][t][lane] = cnt[t];
  __syncthreads();

#pragma unroll
  for (int i = 0; i < 4; ++i) {
    int idx = tid + 256 * i;
    int t = idx >> 6, oc = idx & 63;
    unsigned s = cntL[0][t][oc] + cntL[1][t][oc] + cntL[2][t][oc] + cntL[3][t][oc];
    meanL[t][oc] = (float)s / 129.f;
  }
  __syncthreads();

  if (tid < 32) {
    int o = tid;
    const float* wrow = fc1w + o * 64;
    float bb = fc1b[o];
    float v = 0.f;
    unsigned msk = 0;
    for (int t = 0; t < 16; ++t) {
      float s = 0.f;
      for (int d = 0; d < 64; ++d) s = fmaf(meanL[t][d], wrow[d], s);
      float xin = s + bb;
      v = v + (xin - v) * 0.5f;
      if (v >= 1.f) { msk |= (1u << t); v = 0.f; }
    }
    s3m[o] = msk;
  }
  __syncthreads();

  if (tid < 5) {
    int q = tid;
    const float* wrow = fc2w + q * 32;
    float bb = fc2b[q];
    float accs = 0.f;
    for (int t = 0; t < 16; ++t) {
      float s = 0.f;
      for (int o = 0; o < 32; ++o) s += (((s3m[o] >> t) & 1u) ? wrow[o] : 0.f);
      accs += (s + bb);
    }
    out[b * 5 + q] = accs / 16.f;
  }
}

extern "C" void kernel_launch(void* const* d_in, const int* in_sizes, int n_in,
                              void* d_out, int out_size, void* d_ws, size_t ws_size,
                              hipStream_t stream) {
  const float* x   = (const float*)d_in[0];
  const float* w0  = (const float*)d_in[1];
  const float* b0  = (const float*)d_in[2];
  const float* bng = (const float*)d_in[3];
  const float* bnb = (const float*)d_in[4];
  const float* bnm = (const float*)d_in[5];
  const float* bnv = (const float*)d_in[6];
  const float* w1  = (const float*)d_in[7];
  const float* b1  = (const float*)d_in[8];
  const float* w2  = (const float*)d_in[9];
  const float* b2  = (const float*)d_in[10];
  const float* f1w = (const float*)d_in[11];
  const float* f1b = (const float*)d_in[12];
  const float* f2w = (const float*)d_in[13];
  const float* f2b = (const float*)d_in[14];
  float* out = (float*)d_out;

  char* ws = (char*)d_ws;
  size_t sz_m1 = (size_t)NB * 32 * M1S * 2;      // 8,519,680
  size_t sz_s2 = (size_t)NB * S2R * 64 * 2;      // 4,325,376
  size_t off_s2 = sz_m1;
  size_t off_w2 = off_s2 + sz_s2;
  if (ws_size < off_w2 + 32768) return;          // ~12.9 MB needed

  unsigned short* m1 = (unsigned short*)ws;
  unsigned short* s2 = (unsigned short*)(ws + off_s2);
  float* w2t2 = (float*)(ws + off_w2);

  kF_front<<<NB * 5, 256, 0, stream>>>(x, w0, b0, bng, bnb, bnm, bnv, w1, b1, m1, w2, w2t2);
  kD_conv2_lif<<<NB * 33, 256, 0, stream>>>(m1, w2t2, b2, s2);
  kE_head<<<NB, 256, 0, stream>>>(s2, f1w, f1b, f2w, f2b, out);
}

// Round 10
// 112.227 us; speedup vs baseline: 4.0750x; 1.0385x over previous
//
#include <hip/hip_runtime.h>
#include <math.h>

// HybridSNN: time-collapsed spiking CNN (exact fp32 replication, bit-exact orders).
//  kF: conv0+BN+ReLU+maxpool (full h tile in LDS, R7 structure) + conv1 + LIF -> m1
//      [256][32][520] u16. Phase 2 uses a rolling 3-quad x window (1 b128/position
//      instead of 3). (+w2 repack tail in blocks 0..15 -> w2t2[c][oc][4])
//      R9 lesson: ic-halving put acc[16] live across barriers -> VGPR 84 -> occ 23%.
//  kD: maxpool(OR) + conv2 over bits + LIF2 -> s2 [256][132][64] u16 ([b][j][oc])
//      256-thr/4-wave, wave = 1 j, lane = oc; ballot-compacted c-loop + per-k
//      skips; F rows 80B; weights one coalesced b128/lane per c (w2t2).
//  kE: popcount-mean + fc1 + LIF3 + fc2 -> out [256][5] f32 (lane=oc, coalesced)

#define NB 256
#define LX 4097
#define LQ 2049
#define LP 1025
#define LJ1 513
#define LP1 257
#define LJ2 129

#define M1S 520
#define S2R 132
#define HSW 260   // hs row stride (floats)

typedef float f32x4 __attribute__((ext_vector_type(4)));

// ---------------------------------------------------------------- kF ---------
// grid: 256 b x 5 jt. J0 = jt*128. h positions p in [2*J0-2, 2*J0+258].
__global__ __launch_bounds__(256) void kF_front(const float* __restrict__ x,
                                                const float* __restrict__ w0,
                                                const float* __restrict__ b0,
                                                const float* __restrict__ bng,
                                                const float* __restrict__ bnb,
                                                const float* __restrict__ bnm,
                                                const float* __restrict__ bnv,
                                                const float* __restrict__ w1,
                                                const float* __restrict__ b1,
                                                unsigned short* __restrict__ m1,
                                                const float* __restrict__ w2,
                                                float* __restrict__ w2t2) {
  __shared__ __align__(16) float xs[1056];      //  4224 B  x window (+1 guard quad)
  __shared__ __align__(16) float hs[16 * HSW];  // 16640 B  h tile
  __shared__ __align__(16) float wl[2560];      // 10240 B  w1 transposed
  __shared__ float w0s[112];
  __shared__ float cpar[64];                    // per c: m, g, bb, bc
  __shared__ float rs_l[16];
  int bid = blockIdx.x;
  int b = bid / 5, jt = bid % 5;
  int J0 = jt * 128;
  int Pstart = 2 * J0 - 2;
  int tid = threadIdx.x;

  // ---- phase 1: stage x window, w1 (transposed), conv0 constants
  if (tid < 16) rs_l[tid] = (float)(1.0 / sqrt((double)bnv[tid] + 1e-5));
  {
    const float* xb = x + (size_t)b * LX;
    int xoff = 4 * Pstart - 5;
    for (int i = tid; i < 1056; i += 256) {
      int gi = xoff + i;
      xs[i] = (gi >= 0 && gi < LX) ? xb[gi] : 0.f;
    }
    for (int i = tid; i < 2560; i += 256) {
      int c = i & 31, r = i >> 5;           // r = ic*5 + k
      wl[i] = w1[c * 80 + r];
    }
    if (tid < 112) w0s[tid] = w0[tid];
    if (tid >= 128 && tid < 192) {
      int i = tid - 128;
      int c = i >> 2, e = i & 3;
      float v = (e == 0) ? bnm[c] : (e == 1) ? bng[c] : (e == 2) ? bnb[c] : b0[c];
      cpar[i] = v;
    }
  }
  __syncthreads();

  // ---- phase 2: conv0 + BN + ReLU + maxpool -> hs[c][dp], p = Pstart+dp
  // thread = (c2 = tid>>4, g2 = tid&15), 17 consecutive positions; rolling window
  {
    int c2 = tid >> 4, g2 = tid & 15;
    float m = cpar[4 * c2], g = cpar[4 * c2 + 1], bb = cpar[4 * c2 + 2],
          bc = cpar[4 * c2 + 3];
    float rs = rs_l[c2];
    float wv[7];
#pragma unroll
    for (int k = 0; k < 7; ++k) wv[k] = w0s[c2 * 7 + k];
    int dp0 = g2 * 17;
    const f32x4* xv = (const f32x4*)xs;
    f32x4 q0 = xv[dp0], q1 = xv[dp0 + 1], q2 = xv[dp0 + 2];
#pragma unroll
    for (int i = 0; i < 17; ++i) {
      int dp = dp0 + i;
      if (dp >= 261) break;
      int p = Pstart + dp;
      float hm = 0.f;
      if (p >= 0 && p < LP) {
        float win[12] = {q0.x, q0.y, q0.z, q0.w, q1.x, q1.y, q1.z, q1.w,
                         q2.x, q2.y, q2.z, q2.w};
        float best = -INFINITY;
#pragma unroll
        for (int dq = -1; dq <= 1; ++dq) {
          int q = 2 * p + dq;
          if (q < 0 || q >= LQ) continue;
          float s = 0.f;
          int base = 2 * dq + 2;
#pragma unroll
          for (int k = 0; k < 7; ++k) s = fmaf(win[base + k], wv[k], s);
          float y = s + bc;
          y = (y - m) * rs * g + bb;
          y = fmaxf(y, 0.f);
          best = fmaxf(best, y);
        }
        hm = best;
      }
      hs[c2 * HSW + dp] = hm;
      q0 = q1; q1 = q2; q2 = xv[dp + 3];   // dp+3 <= 263, in bounds (guard quad)
    }
  }
  __syncthreads();

  // ---- phase 3: conv1 + 16-step LIF (const input) -> m1
  {
    int c = tid & 31, jg = tid >> 5;
    int jbase = J0 + jg * 16;
    if (jbase <= 512) {
      float acc[16];
#pragma unroll
      for (int i = 0; i < 16; ++i) acc[i] = 0.f;

      for (int ic = 0; ic < 16; ++ic) {
        float win[36];
        const f32x4* row = (const f32x4*)(hs + ic * HSW + 32 * jg);
#pragma unroll
        for (int i = 0; i < 9; ++i) {
          f32x4 v = row[i];
          win[4 * i] = v.x; win[4 * i + 1] = v.y;
          win[4 * i + 2] = v.z; win[4 * i + 3] = v.w;
        }
        float wv[5];
#pragma unroll
        for (int k = 0; k < 5; ++k) wv[k] = wl[(ic * 5 + k) * 32 + c];
#pragma unroll
        for (int j = 0; j < 16; ++j) {
#pragma unroll
          for (int k = 0; k < 5; ++k) acc[j] = fmaf(win[2 * j + k], wv[k], acc[j]);
        }
      }

      float bc = b1[c];
      unsigned mskv[16];
#pragma unroll
      for (int j = 0; j < 16; ++j) {
        float xin = acc[j] + bc;
        float v = 0.f; unsigned mm = 0;
#pragma unroll
        for (int t = 0; t < 16; ++t) {
          v = v + (xin - v) * 0.5f;
          if (v >= 1.f) { mm |= (1u << t); v = 0.f; }
        }
        mskv[j] = mm;
      }
      size_t rowo = ((size_t)b * 32 + c) * M1S + jbase;
      if (jbase + 15 < LJ1) {
        uint4 u0, u1;
        u0.x = mskv[0] | (mskv[1] << 16);
        u0.y = mskv[2] | (mskv[3] << 16);
        u0.z = mskv[4] | (mskv[5] << 16);
        u0.w = mskv[6] | (mskv[7] << 16);
        u1.x = mskv[8] | (mskv[9] << 16);
        u1.y = mskv[10] | (mskv[11] << 16);
        u1.z = mskv[12] | (mskv[13] << 16);
        u1.w = mskv[14] | (mskv[15] << 16);
        *(uint4*)(m1 + rowo) = u0;
        *(uint4*)(m1 + rowo + 8) = u1;
      } else {
        for (int j = 0; j < 16; ++j)
          if (jbase + j < LJ1) m1[rowo + j] = (unsigned short)mskv[j];
      }
    }
  }

  // ---- tail: w2 repack -> w2t2[c][oc][4] (blocks 0..15)
  if (bid < 16) {
    for (int idx = bid * 256 + tid; idx < 64 * 32 * 3; idx += 4096) {
      int k = idx % 3; int r = idx / 3; int cc = r % 32; int oc = r / 32;
      w2t2[((size_t)cc * 64 + oc) * 4 + k] = w2[idx];
    }
  }
}

// ---------------------------------------------------------------- kD ---------
// grid: 256 b x 33 jt; block 4 waves; wave w -> j = jt*4+w; lane = oc.
__global__ __launch_bounds__(256) void kD_conv2_lif(const unsigned short* __restrict__ m1,
                                                    const float* __restrict__ w2t2,
                                                    const float* __restrict__ b2,
                                                    unsigned short* __restrict__ s2) {
  __shared__ __align__(16) float F[288 * 20];     // 23040 B, 80B rows (conflict-free)
  __shared__ unsigned mval[288];                  //  1152 B
  __shared__ unsigned short mbuf[32 * 20];        //  1280 B
  int bid = blockIdx.x;
  int b = bid / 33, jt = bid % 33;
  int j0 = jt * 4;
  int tid = threadIdx.x;
  int w = tid >> 6;      // wave id = j offset
  int lane = tid & 63;   // oc

  // stage m1 window: q = 4*j0 - 3 + u, u in [0,20)
  const unsigned short* m1b = m1 + (size_t)b * 32 * M1S;
  int qbase = 4 * j0 - 3;
  for (int i = tid; i < 1024; i += 256) {
    int c = i >> 5, u = i & 31;
    if (u < 20) {
      int q = qbase + u;
      mbuf[c * 20 + u] = (q >= 0 && q <= 512) ? m1b[(size_t)c * M1S + q] : (unsigned short)0;
    }
  }
  __syncthreads();

  // build F rows + mval: 288 = 32 c x 9 positions (maxpool-OR folded)
  for (int it = tid; it < 288; it += 256) {
    int c = it / 9, idx = it - c * 9;
    int p = 2 * j0 - 1 + idx;
    unsigned m = 0;
    if (p >= 0 && p < LP1) {
      const unsigned short* mr = mbuf + c * 20;
      int l0 = 2 * idx;
      m = (unsigned)mr[l0] | (unsigned)mr[l0 + 1] | (unsigned)mr[l0 + 2];
    }
    mval[it] = m;
    f32x4* Fr = (f32x4*)(F + it * 20);
    f32x4 f0, f1, f2, f3;
    f0.x = (float)(m & 1u);         f0.y = (float)((m >> 1) & 1u);
    f0.z = (float)((m >> 2) & 1u);  f0.w = (float)((m >> 3) & 1u);
    f1.x = (float)((m >> 4) & 1u);  f1.y = (float)((m >> 5) & 1u);
    f1.z = (float)((m >> 6) & 1u);  f1.w = (float)((m >> 7) & 1u);
    f2.x = (float)((m >> 8) & 1u);  f2.y = (float)((m >> 9) & 1u);
    f2.z = (float)((m >> 10) & 1u); f2.w = (float)((m >> 11) & 1u);
    f3.x = (float)((m >> 12) & 1u); f3.y = (float)((m >> 13) & 1u);
    f3.z = (float)((m >> 14) & 1u); f3.w = (float)((m >> 15) & 1u);
    Fr[0] = f0; Fr[1] = f1; Fr[2] = f2; Fr[3] = f3;
  }
  __syncthreads();

  // ballot-compact nonzero channels for this wave's j (3-position window)
  unsigned bits;
  {
    bool nz = false;
    if (lane < 32) {
      int base9 = lane * 9 + 2 * w;
      nz = (mval[base9] | mval[base9 + 1] | mval[base9 + 2]) != 0u;
    }
    bits = (unsigned)__ballot(nz);
  }

  float acc[16];
#pragma unroll
  for (int t = 0; t < 16; ++t) acc[t] = 0.f;

  const f32x4* wbase = (const f32x4*)w2t2 + lane;  // + c*64 -> [c][oc][4]
  while (bits) {
    int c = __builtin_ctz(bits);
    bits &= bits - 1;
    int base9 = c * 9 + 2 * w;
    unsigned mv0 = mval[base9];
    unsigned mv1 = mval[base9 + 1];
    unsigned mv2 = mval[base9 + 2];
    f32x4 wq = wbase[c * 64];          // one coalesced b128: w[k=0..2] (+pad)
    const float* Fb = F + base9 * 20;
    if (mv0) {
      const f32x4* Fp = (const f32x4*)Fb;
      f32x4 fv[4];
      fv[0] = Fp[0]; fv[1] = Fp[1]; fv[2] = Fp[2]; fv[3] = Fp[3];
#pragma unroll
      for (int t = 0; t < 16; ++t) acc[t] = fmaf(wq.x, fv[t >> 2][t & 3], acc[t]);
    }
    if (mv1) {
      const f32x4* Fp = (const f32x4*)(Fb + 20);
      f32x4 fv[4];
      fv[0] = Fp[0]; fv[1] = Fp[1]; fv[2] = Fp[2]; fv[3] = Fp[3];
#pragma unroll
      for (int t = 0; t < 16; ++t) acc[t] = fmaf(wq.y, fv[t >> 2][t & 3], acc[t]);
    }
    if (mv2) {
      const f32x4* Fp = (const f32x4*)(Fb + 40);
      f32x4 fv[4];
      fv[0] = Fp[0]; fv[1] = Fp[1]; fv[2] = Fp[2]; fv[3] = Fp[3];
#pragma unroll
      for (int t = 0; t < 16; ++t) acc[t] = fmaf(wq.z, fv[t >> 2][t & 3], acc[t]);
    }
  }

  int j = j0 + w;
  if (j < LJ2) {
    float bc = b2[lane];
    float v = 0.f; unsigned mm = 0;
#pragma unroll
    for (int t = 0; t < 16; ++t) {
      float xin = acc[t] + bc;
      v = v + (xin - v) * 0.5f;
      if (v >= 1.f) { mm |= (1u << t); v = 0.f; }
    }
    s2[((size_t)b * S2R + j) * 64 + lane] = (unsigned short)mm;  // coalesced
  }
}

// ---------------------------------------------------------------- kE ---------
// block = 256 thr per b; wave = j chunk, lane = oc (coalesced 128B rows)
__global__ __launch_bounds__(256) void kE_head(const unsigned short* __restrict__ s2,
                                               const float* __restrict__ fc1w,
                                               const float* __restrict__ fc1b,
                                               const float* __restrict__ fc2w,
                                               const float* __restrict__ fc2b,
                                               float* __restrict__ out) {
  __shared__ unsigned cntL[4][16][64];   // 16 KB
  __shared__ float meanL[16][64];        //  4 KB
  __shared__ unsigned s3m[32];
  int b = blockIdx.x;
  int tid = threadIdx.x;
  int w = tid >> 6, lane = tid & 63;

  int j0 = (w == 0) ? 0 : 33 + 32 * (w - 1);
  int jc = (w == 0) ? 33 : 32;
  const unsigned short* base = s2 + (size_t)b * S2R * 64 + lane;
  unsigned cnt[16];
#pragma unroll
  for (int t = 0; t < 16; ++t) cnt[t] = 0;
  for (int u = 0; u < jc; ++u) {
    unsigned m = base[(size_t)(j0 + u) * 64];
#pragma unroll
    for (int t = 0; t < 16; ++t) cnt[t] += (m >> t) & 1u;
  }
#pragma unroll
  for (int t = 0; t < 16; ++t) cntL[w][t][lane] = cnt[t];
  __syncthreads();

#pragma unroll
  for (int i = 0; i < 4; ++i) {
    int idx = tid + 256 * i;
    int t = idx >> 6, oc = idx & 63;
    unsigned s = cntL[0][t][oc] + cntL[1][t][oc] + cntL[2][t][oc] + cntL[3][t][oc];
    meanL[t][oc] = (float)s / 129.f;
  }
  __syncthreads();

  if (tid < 32) {
    int o = tid;
    const float* wrow = fc1w + o * 64;
    float bb = fc1b[o];
    float v = 0.f;
    unsigned msk = 0;
    for (int t = 0; t < 16; ++t) {
      float s = 0.f;
      for (int d = 0; d < 64; ++d) s = fmaf(meanL[t][d], wrow[d], s);
      float xin = s + bb;
      v = v + (xin - v) * 0.5f;
      if (v >= 1.f) { msk |= (1u << t); v = 0.f; }
    }
    s3m[o] = msk;
  }
  __syncthreads();

  if (tid < 5) {
    int q = tid;
    const float* wrow = fc2w + q * 32;
    float bb = fc2b[q];
    float accs = 0.f;
    for (int t = 0; t < 16; ++t) {
      float s = 0.f;
      for (int o = 0; o < 32; ++o) s += (((s3m[o] >> t) & 1u) ? wrow[o] : 0.f);
      accs += (s + bb);
    }
    out[b * 5 + q] = accs / 16.f;
  }
}

extern "C" void kernel_launch(void* const* d_in, const int* in_sizes, int n_in,
                              void* d_out, int out_size, void* d_ws, size_t ws_size,
                              hipStream_t stream) {
  const float* x   = (const float*)d_in[0];
  const float* w0  = (const float*)d_in[1];
  const float* b0  = (const float*)d_in[2];
  const float* bng = (const float*)d_in[3];
  const float* bnb = (const float*)d_in[4];
  const float* bnm = (const float*)d_in[5];
  const float* bnv = (const float*)d_in[6];
  const float* w1  = (const float*)d_in[7];
  const float* b1  = (const float*)d_in[8];
  const float* w2  = (const float*)d_in[9];
  const float* b2  = (const float*)d_in[10];
  const float* f1w = (const float*)d_in[11];
  const float* f1b = (const float*)d_in[12];
  const float* f2w = (const float*)d_in[13];
  const float* f2b = (const float*)d_in[14];
  float* out = (float*)d_out;

  char* ws = (char*)d_ws;
  size_t sz_m1 = (size_t)NB * 32 * M1S * 2;      // 8,519,680
  size_t sz_s2 = (size_t)NB * S2R * 64 * 2;      // 4,325,376
  size_t off_s2 = sz_m1;
  size_t off_w2 = off_s2 + sz_s2;
  if (ws_size < off_w2 + 32768) return;          // ~12.9 MB needed

  unsigned short* m1 = (unsigned short*)ws;
  unsigned short* s2 = (unsigned short*)(ws + off_s2);
  float* w2t2 = (float*)(ws + off_w2);

  kF_front<<<NB * 5, 256, 0, stream>>>(x, w0, b0, bng, bnb, bnm, bnv, w1, b1, m1, w2, w2t2);
  kD_conv2_lif<<<NB * 33, 256, 0, stream>>>(m1, w2t2, b2, s2);
  kE_head<<<NB, 256, 0, stream>>>(s2, f1w, f1b, f2w, f2b, out);
}